// Round 2
// baseline (464.476 us; speedup 1.0000x reference)
//
#include <hip/hip_runtime.h>
#include <math.h>

#define PI_F        3.14159265358979323846f
#define TWO_PI_F    6.2831853071795864769f
#define INV_TWO_PI_F 0.15915494309189533577f

// ------------------------------------------------------------------
// GEMM: y[r][c] = sum_k x[r][k] * W[c][k],  K=256, Do=64
// block = 256 threads, tile = (16*RPT) rows x 64 cols,
// thread = RPT rows x 4 cols, register double-buffered k-loop.
// ------------------------------------------------------------------
template<int RPT>
__global__ __launch_bounds__(256) void gemm_xwT_kernel(
    const float* __restrict__ x,
    const float* __restrict__ W,
    float* __restrict__ y)
{
    const int tid = threadIdx.x;
    const int tx  = tid & 15;              // col group: cols 4*tx .. 4*tx+3
    const int ty  = tid >> 4;              // row group
    const long rb = (long)blockIdx.x * (16 * RPT) + (long)ty * RPT;
    const int c0  = tx << 2;

    const float* xp = x + rb * 256;
    const float* wp = W + (long)c0 * 256;

    float4 xa[RPT], wa[4], xb[RPT], wb[4];
    float acc[RPT][4];
    #pragma unroll
    for (int i = 0; i < RPT; ++i)
        #pragma unroll
        for (int j = 0; j < 4; ++j) acc[i][j] = 0.0f;

    // prologue: stage k=0
    #pragma unroll
    for (int i = 0; i < RPT; ++i) xa[i] = *(const float4*)(xp + i * 256);
    #pragma unroll
    for (int j = 0; j < 4;   ++j) wa[j] = *(const float4*)(wp + j * 256);

#define FMA_STEP(xv, wv)                                           \
    _Pragma("unroll")                                              \
    for (int i = 0; i < RPT; ++i) {                                \
        _Pragma("unroll")                                          \
        for (int j = 0; j < 4; ++j) {                              \
            acc[i][j] = fmaf(xv[i].x, wv[j].x, acc[i][j]);         \
            acc[i][j] = fmaf(xv[i].y, wv[j].y, acc[i][j]);         \
            acc[i][j] = fmaf(xv[i].z, wv[j].z, acc[i][j]);         \
            acc[i][j] = fmaf(xv[i].w, wv[j].w, acc[i][j]);         \
        }                                                          \
    }

    #pragma unroll 1
    for (int k = 0; k < 248; k += 8) {
        // stage k+4 into B while computing k from A
        #pragma unroll
        for (int i = 0; i < RPT; ++i) xb[i] = *(const float4*)(xp + i * 256 + k + 4);
        #pragma unroll
        for (int j = 0; j < 4;   ++j) wb[j] = *(const float4*)(wp + j * 256 + k + 4);
        FMA_STEP(xa, wa)
        // stage k+8 into A while computing k+4 from B
        #pragma unroll
        for (int i = 0; i < RPT; ++i) xa[i] = *(const float4*)(xp + i * 256 + k + 8);
        #pragma unroll
        for (int j = 0; j < 4;   ++j) wa[j] = *(const float4*)(wp + j * 256 + k + 8);
        FMA_STEP(xb, wb)
    }
    // epilogue: k = 248, 252
    #pragma unroll
    for (int i = 0; i < RPT; ++i) xb[i] = *(const float4*)(xp + i * 256 + 252);
    #pragma unroll
    for (int j = 0; j < 4;   ++j) wb[j] = *(const float4*)(wp + j * 256 + 252);
    FMA_STEP(xa, wa)
    FMA_STEP(xb, wb)

#undef FMA_STEP

    #pragma unroll
    for (int i = 0; i < RPT; ++i)
        *(float4*)(y + (rb + i) * 64 + c0) =
            make_float4(acc[i][0], acc[i][1], acc[i][2], acc[i][3]);
}

// ------------------------------------------------------------------
// Projection: per group g, neighbors nh[g][0..7]:
//   logw[p][j] = -(dlat^2+dlon_w^2)/(2 sigma^2) + kappa*(cos(dlon_w)-1)
//   w = softmax_j(logw);  out[n=g*GS+p][d] = sum_j w[p][j]*y[nh[g][j]][d]
// One wave handles CG groups (CG*GS == ROUNDS*8 point-slots).
// ------------------------------------------------------------------
template<int GS, int CG, int ROUNDS>
__global__ __launch_bounds__(256) void proj_kernel(
    const float* __restrict__ y,       // [B*N][64]
    const float* __restrict__ coords,  // [2][N]
    const int*   __restrict__ nh,      // [N][8]
    const float* __restrict__ oc,      // [2][B][N0]
    const float* __restrict__ sig_p,
    const float* __restrict__ kap_p,
    float* __restrict__ out,           // [B][N0][64]
    int N, int N0)
{
    constexpr int B = 2;
    static_assert(CG * GS == ROUNDS * 8, "slot layout");
    __shared__ float wlds[4][ROUNDS * 64];

    const int wslot = threadIdx.x >> 6;
    const int lane  = threadIdx.x & 63;
    const int wave  = (blockIdx.x << 2) + wslot;    // global wave id
    const int gpb   = N / CG;                       // group-chunks per batch
    const int b     = wave / gpb;
    const int g0    = (wave - b * gpb) * CG;

    const float sigma  = *sig_p;
    const float kappa  = *kap_p;
    const float inv2s2 = 1.0f / (2.0f * sigma * sigma);

    const int j  = lane & 7;
    const int pp = lane >> 3;

    #pragma unroll
    for (int r = 0; r < ROUNDS; ++r) {
        const int pidx = r * 8 + pp;
        const int q = pidx / GS;
        const int p = pidx - q * GS;
        const int g = g0 + q;
        const int idx = nh[g * 8 + j];
        const float clon = coords[idx];
        const float clat = coords[N + idx];
        const int n = g * GS + p;
        const float olon = oc[(long)b * N0 + n];
        const float olat = oc[(long)(B + b) * N0 + n];

        float dlon = olon - clon;
        float t = (dlon + PI_F) * INV_TWO_PI_F;   // floor-mod wrap to [-pi, pi)
        t -= floorf(t);
        dlon = t * TWO_PI_F - PI_F;
        const float dlat = olat - clat;

        float logw = -(dlat * dlat + dlon * dlon) * inv2s2
                   + kappa * (cosf(dlon) - 1.0f);

        // softmax over the 8 neighbor lanes
        float m = logw;
        m = fmaxf(m, __shfl_xor(m, 1));
        m = fmaxf(m, __shfl_xor(m, 2));
        m = fmaxf(m, __shfl_xor(m, 4));
        float e = expf(logw - m);
        float s = e;
        s += __shfl_xor(s, 1);
        s += __shfl_xor(s, 2);
        s += __shfl_xor(s, 4);
        wlds[wslot][r * 64 + lane] = e / s;
    }

    __syncthreads();

    const int d = lane;                 // channel
    const float* yb = y + (long)b * N * 64 + d;
    #pragma unroll
    for (int pidx = 0; pidx < CG * GS; ++pidx) {
        const int q = pidx / GS;
        const int p = pidx - q * GS;
        const int g = g0 + q;
        const int* nhg = nh + g * 8;
        const float* wrow = &wlds[wslot][pidx * 8];
        float a = 0.0f;
        #pragma unroll
        for (int jj = 0; jj < 8; ++jj)
            a = fmaf(wrow[jj], yb[(long)nhg[jj] * 64], a);
        const int n = g * GS + p;
        out[((long)b * N0 + n) * 64 + d] = a;
    }
}

// ------------------------------------------------------------------
extern "C" void kernel_launch(void* const* d_in, const int* in_sizes, int n_in,
                              void* d_out, int out_size, void* d_ws, size_t ws_size,
                              hipStream_t stream)
{
    const float* x0   = (const float*)d_in[0];
    const float* x1   = (const float*)d_in[1];
    const float* x2   = (const float*)d_in[2];
    const float* W0   = (const float*)d_in[3];
    const float* W1   = (const float*)d_in[4];
    const float* W2   = (const float*)d_in[5];
    const float* sig0 = (const float*)d_in[6];
    const float* sig1 = (const float*)d_in[7];
    const float* sig2 = (const float*)d_in[8];
    const float* kap0 = (const float*)d_in[9];
    const float* kap1 = (const float*)d_in[10];
    const float* kap2 = (const float*)d_in[11];
    const float* c0   = (const float*)d_in[12];
    const float* c1   = (const float*)d_in[13];
    const float* c2   = (const float*)d_in[14];
    const int*   nh0  = (const int*)d_in[15];
    const int*   nh1  = (const int*)d_in[16];
    const int*   nh2  = (const int*)d_in[17];
    const float* oc   = (const float*)d_in[18];

    float* out = (float*)d_out;
    const size_t SLICE = (size_t)2 * 65536 * 64;   // floats per output level slice
    // Stage y0/y1 in the out slice for level 2 (written before slice 2's final
    // contents are produced); y2 (2.1 MB) goes in d_ws.
    float* ystage = out + 2 * SLICE;
    float* y2     = (float*)d_ws;

    // ---- level 0: N=65536 rows=131072, tile 64 rows -> 2048 blocks
    gemm_xwT_kernel<4><<<131072 / 64, 256, 0, stream>>>(x0, W0, ystage);
    proj_kernel<1, 8, 1><<<(2 * 65536 / 8) / 4, 256, 0, stream>>>(
        ystage, c0, nh0, oc, sig0, kap0, out + 0 * SLICE, 65536, 65536);

    // ---- level 1: rows=32768, tile 64 rows -> 512 blocks
    gemm_xwT_kernel<4><<<32768 / 64, 256, 0, stream>>>(x1, W1, ystage);
    proj_kernel<4, 2, 1><<<(2 * 16384 / 2) / 4, 256, 0, stream>>>(
        ystage, c1, nh1, oc, sig1, kap1, out + 1 * SLICE, 16384, 65536);

    // ---- level 2: rows=8192, tile 32 rows -> 256 blocks
    gemm_xwT_kernel<2><<<8192 / 32, 256, 0, stream>>>(x2, W2, y2);
    proj_kernel<16, 1, 2><<<(2 * 4096 / 1) / 4, 256, 0, stream>>>(
        y2, c2, nh2, oc, sig2, kap2, out + 2 * SLICE, 4096, 65536);
}

// Round 3
// 133.239 us; speedup vs baseline: 3.4860x; 3.4860x over previous
//
#include <hip/hip_runtime.h>
#include <math.h>

#define PI_F        3.14159265358979323846f
#define TWO_PI_F    6.2831853071795864769f
#define INV_TWO_PI_F 0.15915494309189533577f

typedef __attribute__((ext_vector_type(8))) short bf16x8;
typedef __attribute__((ext_vector_type(4))) float f32x4;

__device__ inline short f2bf(float f) {
    unsigned u = __builtin_bit_cast(unsigned, f);
    unsigned r = (u + 0x7FFFu + ((u >> 16) & 1u)) >> 16;
    return (short)r;
}

// ------------------------------------------------------------------
// bf16-MFMA GEMM: y[r][c] = sum_k x[r][k] * W[c][k], K=256, Do=64.
// Block: 256 thr (4 waves, 2x2 wave grid). Tile: M = MT*32 rows x 64 cols.
// W-frags live in registers (converted f32->bf16 once per block).
// x staged f32->bf16 into swizzled LDS, double buffered, BK=64.
// MFMA 16x16x32: A(m,k): lane=(k>>3)*16+m, slot k&7 (contiguous 8 k).
//                B(k,n): lane=(k>>3)*16+n, slot k&7 -> W[n][k..k+7] row-major.
//                C(m,n): n=lane&15, m=(lane>>4)*4+reg.
// ------------------------------------------------------------------
template<int MT>   // m-tiles (16 rows each) per wave; block M = MT*32
__global__ __launch_bounds__(256) void gemm_mfma(
    const float* __restrict__ x,     // [R][256]
    const float* __restrict__ W,     // [64][256]
    float* __restrict__ y)           // [R][64]
{
    constexpr int M  = MT * 32;
    constexpr int SW = MT / 2;       // staging sweeps of 64 rows
    __shared__ short lds[2][M * 64]; // bf16 [M][64], 16B-chunk XOR-swizzled

    const int tid  = threadIdx.x;
    const int lane = tid & 63;
    const int w    = tid >> 6;
    const int wm   = w >> 1;                 // m-group (0/1)
    const int wn   = w & 1;                  // n-group (0/1)
    const int l16  = lane & 15;
    const int lq   = lane >> 4;
    const long rowbase = (long)blockIdx.x * M;

    // ---- W fragments -> registers: wf[n-tile][k-slice(32)]
    bf16x8 wf[2][8];
    {
        #pragma unroll
        for (int nt = 0; nt < 2; ++nt) {
            const int col = wn * 32 + nt * 16 + l16;
            const float* wp = W + (long)col * 256 + lq * 8;
            #pragma unroll
            for (int ks = 0; ks < 8; ++ks) {
                f32x4 a = *(const f32x4*)(wp + ks * 32);
                f32x4 b = *(const f32x4*)(wp + ks * 32 + 4);
                bf16x8 f;
                f[0]=f2bf(a.x); f[1]=f2bf(a.y); f[2]=f2bf(a.z); f[3]=f2bf(a.w);
                f[4]=f2bf(b.x); f[5]=f2bf(b.y); f[6]=f2bf(b.z); f[7]=f2bf(b.w);
                wf[nt][ks] = f;
            }
        }
    }

    f32x4 acc[MT][2];
    #pragma unroll
    for (int mt = 0; mt < MT; ++mt)
        #pragma unroll
        for (int nt = 0; nt < 2; ++nt)
            acc[mt][nt] = f32x4{0.f, 0.f, 0.f, 0.f};

    const int srow = tid >> 2;               // 0..63
    const int sq   = tid & 3;                // 16-float k-segment

    f32x4 st[SW][4];

#define LOADC(CH)                                                            \
    { _Pragma("unroll")                                                      \
      for (int s = 0; s < SW; ++s) {                                         \
          const float* xp = x + (rowbase + s * 64 + srow) * 256              \
                              + (CH) * 64 + sq * 16;                         \
          _Pragma("unroll")                                                  \
          for (int q = 0; q < 4; ++q) st[s][q] = *(const f32x4*)(xp + q*4);  \
      } }

#define WRITEC(BUF)                                                          \
    { _Pragma("unroll")                                                      \
      for (int s = 0; s < SW; ++s) {                                         \
          const int row = s * 64 + srow;                                     \
          bf16x8 lo, hi;                                                     \
          lo[0]=f2bf(st[s][0].x); lo[1]=f2bf(st[s][0].y);                    \
          lo[2]=f2bf(st[s][0].z); lo[3]=f2bf(st[s][0].w);                    \
          lo[4]=f2bf(st[s][1].x); lo[5]=f2bf(st[s][1].y);                    \
          lo[6]=f2bf(st[s][1].z); lo[7]=f2bf(st[s][1].w);                    \
          hi[0]=f2bf(st[s][2].x); hi[1]=f2bf(st[s][2].y);                    \
          hi[2]=f2bf(st[s][2].z); hi[3]=f2bf(st[s][2].w);                    \
          hi[4]=f2bf(st[s][3].x); hi[5]=f2bf(st[s][3].y);                    \
          hi[6]=f2bf(st[s][3].z); hi[7]=f2bf(st[s][3].w);                    \
          const int c0 = 2 * sq, c1 = 2 * sq + 1, rs = row & 7;              \
          *(bf16x8*)&lds[BUF][row * 64 + ((c0 ^ rs) << 3)] = lo;             \
          *(bf16x8*)&lds[BUF][row * 64 + ((c1 ^ rs) << 3)] = hi;             \
      } }

    LOADC(0)
    WRITEC(0)
    __syncthreads();

    #pragma unroll
    for (int c = 0; c < 4; ++c) {
        if (c < 3) LOADC(c + 1)                     // issue next-chunk loads early
        // ---- MFMA on buffer c&1
        #pragma unroll
        for (int ks = 0; ks < 2; ++ks) {
            #pragma unroll
            for (int mt = 0; mt < MT; ++mt) {
                const int row = wm * (MT * 16) + mt * 16 + l16;
                const int ch  = ks * 4 + lq;
                bf16x8 af = *(const bf16x8*)
                    &lds[c & 1][row * 64 + ((ch ^ (row & 7)) << 3)];
                acc[mt][0] = __builtin_amdgcn_mfma_f32_16x16x32_bf16(
                    af, wf[0][c * 2 + ks], acc[mt][0], 0, 0, 0);
                acc[mt][1] = __builtin_amdgcn_mfma_f32_16x16x32_bf16(
                    af, wf[1][c * 2 + ks], acc[mt][1], 0, 0, 0);
            }
        }
        if (c < 3) {
            WRITEC((c + 1) & 1)                     // write-late into other buffer
            __syncthreads();
        }
    }
#undef LOADC
#undef WRITEC

    // ---- epilogue: C(m,n): n = lane&15, m = (lane>>4)*4 + j
    #pragma unroll
    for (int mt = 0; mt < MT; ++mt) {
        const long row0 = rowbase + wm * (MT * 16) + mt * 16 + lq * 4;
        #pragma unroll
        for (int nt = 0; nt < 2; ++nt) {
            const int col = wn * 32 + nt * 16 + l16;
            #pragma unroll
            for (int j = 0; j < 4; ++j)
                y[(row0 + j) * 64 + col] = acc[mt][nt][j];
        }
    }
}

// ------------------------------------------------------------------
// Projection (unchanged from round 1)
// ------------------------------------------------------------------
template<int GS, int CG, int ROUNDS>
__global__ __launch_bounds__(256) void proj_kernel(
    const float* __restrict__ y,       // [B*N][64]
    const float* __restrict__ coords,  // [2][N]
    const int*   __restrict__ nh,      // [N][8]
    const float* __restrict__ oc,      // [2][B][N0]
    const float* __restrict__ sig_p,
    const float* __restrict__ kap_p,
    float* __restrict__ out,           // [B][N0][64]
    int N, int N0)
{
    constexpr int B = 2;
    static_assert(CG * GS == ROUNDS * 8, "slot layout");
    __shared__ float wlds[4][ROUNDS * 64];

    const int wslot = threadIdx.x >> 6;
    const int lane  = threadIdx.x & 63;
    const int wave  = (blockIdx.x << 2) + wslot;
    const int gpb   = N / CG;
    const int b     = wave / gpb;
    const int g0    = (wave - b * gpb) * CG;

    const float sigma  = *sig_p;
    const float kappa  = *kap_p;
    const float inv2s2 = 1.0f / (2.0f * sigma * sigma);

    const int j  = lane & 7;
    const int pp = lane >> 3;

    #pragma unroll
    for (int r = 0; r < ROUNDS; ++r) {
        const int pidx = r * 8 + pp;
        const int q = pidx / GS;
        const int p = pidx - q * GS;
        const int g = g0 + q;
        const int idx = nh[g * 8 + j];
        const float clon = coords[idx];
        const float clat = coords[N + idx];
        const int n = g * GS + p;
        const float olon = oc[(long)b * N0 + n];
        const float olat = oc[(long)(B + b) * N0 + n];

        float dlon = olon - clon;
        float t = (dlon + PI_F) * INV_TWO_PI_F;
        t -= floorf(t);
        dlon = t * TWO_PI_F - PI_F;
        const float dlat = olat - clat;

        float logw = -(dlat * dlat + dlon * dlon) * inv2s2
                   + kappa * (cosf(dlon) - 1.0f);

        float m = logw;
        m = fmaxf(m, __shfl_xor(m, 1));
        m = fmaxf(m, __shfl_xor(m, 2));
        m = fmaxf(m, __shfl_xor(m, 4));
        float e = expf(logw - m);
        float s = e;
        s += __shfl_xor(s, 1);
        s += __shfl_xor(s, 2);
        s += __shfl_xor(s, 4);
        wlds[wslot][r * 64 + lane] = e / s;
    }

    __syncthreads();

    const int d = lane;
    const float* yb = y + (long)b * N * 64 + d;
    #pragma unroll
    for (int pidx = 0; pidx < CG * GS; ++pidx) {
        const int q = pidx / GS;
        const int p = pidx - q * GS;
        const int g = g0 + q;
        const int* nhg = nh + g * 8;
        const float* wrow = &wlds[wslot][pidx * 8];
        float a = 0.0f;
        #pragma unroll
        for (int jj = 0; jj < 8; ++jj)
            a = fmaf(wrow[jj], yb[(long)nhg[jj] * 64], a);
        const int n = g * GS + p;
        out[((long)b * N0 + n) * 64 + d] = a;
    }
}

// ------------------------------------------------------------------
extern "C" void kernel_launch(void* const* d_in, const int* in_sizes, int n_in,
                              void* d_out, int out_size, void* d_ws, size_t ws_size,
                              hipStream_t stream)
{
    const float* x0   = (const float*)d_in[0];
    const float* x1   = (const float*)d_in[1];
    const float* x2   = (const float*)d_in[2];
    const float* W0   = (const float*)d_in[3];
    const float* W1   = (const float*)d_in[4];
    const float* W2   = (const float*)d_in[5];
    const float* sig0 = (const float*)d_in[6];
    const float* sig1 = (const float*)d_in[7];
    const float* sig2 = (const float*)d_in[8];
    const float* kap0 = (const float*)d_in[9];
    const float* kap1 = (const float*)d_in[10];
    const float* kap2 = (const float*)d_in[11];
    const float* c0   = (const float*)d_in[12];
    const float* c1   = (const float*)d_in[13];
    const float* c2   = (const float*)d_in[14];
    const int*   nh0  = (const int*)d_in[15];
    const int*   nh1  = (const int*)d_in[16];
    const int*   nh2  = (const int*)d_in[17];
    const float* oc   = (const float*)d_in[18];

    float* out = (float*)d_out;
    const size_t SLICE = (size_t)2 * 65536 * 64;
    float* ystage = out + 2 * SLICE;   // staged y0/y1 (slice 2 written last)
    float* y2     = (float*)d_ws;

    // ---- level 0: rows=131072, tile M=128 -> 1024 blocks
    gemm_mfma<4><<<131072 / 128, 256, 0, stream>>>(x0, W0, ystage);
    proj_kernel<1, 8, 1><<<(2 * 65536 / 8) / 4, 256, 0, stream>>>(
        ystage, c0, nh0, oc, sig0, kap0, out + 0 * SLICE, 65536, 65536);

    // ---- level 1: rows=32768, tile M=128 -> 256 blocks
    gemm_mfma<4><<<32768 / 128, 256, 0, stream>>>(x1, W1, ystage);
    proj_kernel<4, 2, 1><<<(2 * 16384 / 2) / 4, 256, 0, stream>>>(
        ystage, c1, nh1, oc, sig1, kap1, out + 1 * SLICE, 16384, 65536);

    // ---- level 2: rows=8192, tile M=64 -> 128 blocks
    gemm_mfma<2><<<8192 / 64, 256, 0, stream>>>(x2, W2, y2);
    proj_kernel<16, 1, 2><<<(2 * 4096 / 1) / 4, 256, 0, stream>>>(
        y2, c2, nh2, oc, sig2, kap2, out + 2 * SLICE, 4096, 65536);
}

// Round 4
// 132.913 us; speedup vs baseline: 3.4946x; 1.0025x over previous
//
#include <hip/hip_runtime.h>
#include <math.h>

#define PI_F        3.14159265358979323846f
#define TWO_PI_F    6.2831853071795864769f
#define INV_TWO_PI_F 0.15915494309189533577f

typedef __attribute__((ext_vector_type(8))) short bf16x8;
typedef __attribute__((ext_vector_type(4))) float f32x4;

__device__ inline short f2bf(float f) {
    unsigned u = __builtin_bit_cast(unsigned, f);
    unsigned r = (u + 0x7FFFu + ((u >> 16) & 1u)) >> 16;
    return (short)r;
}

// ------------------------------------------------------------------
// bf16-MFMA GEMM: y[r][c] = sum_k x[r][k] * W[c][k], K=256, Do=64.
// Block: 256 thr (4 waves, 2x2 wave grid). Tile: M = MT*32 rows x 64 cols.
// W-frags live in registers (converted f32->bf16 once per block).
// x staged f32->bf16 into swizzled LDS, double buffered, BK=64.
// MFMA 16x16x32: A(m,k): lane=(k>>3)*16+m, slot k&7 (contiguous 8 k).
//                B(k,n): lane=(k>>3)*16+n, slot k&7 -> W[n][k..k+7] row-major.
//                C(m,n): n=lane&15, m=(lane>>4)*4+reg.
// ------------------------------------------------------------------
template<int MT>   // m-tiles (16 rows each) per wave; block M = MT*32
__global__ __launch_bounds__(256) void gemm_mfma(
    const float* __restrict__ x,     // [R][256]
    const float* __restrict__ W,     // [64][256]
    float* __restrict__ y)           // [R][64]
{
    constexpr int M  = MT * 32;
    constexpr int SW = MT / 2;       // staging sweeps of 64 rows
    __shared__ short lds[2][M * 64]; // bf16 [M][64], 16B-chunk XOR-swizzled

    const int tid  = threadIdx.x;
    const int lane = tid & 63;
    const int w    = tid >> 6;
    const int wm   = w >> 1;                 // m-group (0/1)
    const int wn   = w & 1;                  // n-group (0/1)
    const int l16  = lane & 15;
    const int lq   = lane >> 4;
    const long rowbase = (long)blockIdx.x * M;

    // ---- W fragments -> registers: wf[n-tile][k-slice(32)]
    bf16x8 wf[2][8];
    {
        #pragma unroll
        for (int nt = 0; nt < 2; ++nt) {
            const int col = wn * 32 + nt * 16 + l16;
            const float* wp = W + (long)col * 256 + lq * 8;
            #pragma unroll
            for (int ks = 0; ks < 8; ++ks) {
                f32x4 a = *(const f32x4*)(wp + ks * 32);
                f32x4 b = *(const f32x4*)(wp + ks * 32 + 4);
                bf16x8 f;
                f[0]=f2bf(a.x); f[1]=f2bf(a.y); f[2]=f2bf(a.z); f[3]=f2bf(a.w);
                f[4]=f2bf(b.x); f[5]=f2bf(b.y); f[6]=f2bf(b.z); f[7]=f2bf(b.w);
                wf[nt][ks] = f;
            }
        }
    }

    f32x4 acc[MT][2];
    #pragma unroll
    for (int mt = 0; mt < MT; ++mt)
        #pragma unroll
        for (int nt = 0; nt < 2; ++nt)
            acc[mt][nt] = f32x4{0.f, 0.f, 0.f, 0.f};

    const int srow = tid >> 2;               // 0..63
    const int sq   = tid & 3;                // 16-float k-segment

    f32x4 st[SW][4];

#define LOADC(CH)                                                            \
    { _Pragma("unroll")                                                      \
      for (int s = 0; s < SW; ++s) {                                         \
          const float* xp = x + (rowbase + s * 64 + srow) * 256              \
                              + (CH) * 64 + sq * 16;                         \
          _Pragma("unroll")                                                  \
          for (int q = 0; q < 4; ++q) st[s][q] = *(const f32x4*)(xp + q*4);  \
      } }

#define WRITEC(BUF)                                                          \
    { _Pragma("unroll")                                                      \
      for (int s = 0; s < SW; ++s) {                                         \
          const int row = s * 64 + srow;                                     \
          bf16x8 lo, hi;                                                     \
          lo[0]=f2bf(st[s][0].x); lo[1]=f2bf(st[s][0].y);                    \
          lo[2]=f2bf(st[s][0].z); lo[3]=f2bf(st[s][0].w);                    \
          lo[4]=f2bf(st[s][1].x); lo[5]=f2bf(st[s][1].y);                    \
          lo[6]=f2bf(st[s][1].z); lo[7]=f2bf(st[s][1].w);                    \
          hi[0]=f2bf(st[s][2].x); hi[1]=f2bf(st[s][2].y);                    \
          hi[2]=f2bf(st[s][2].z); hi[3]=f2bf(st[s][2].w);                    \
          hi[4]=f2bf(st[s][3].x); hi[5]=f2bf(st[s][3].y);                    \
          hi[6]=f2bf(st[s][3].z); hi[7]=f2bf(st[s][3].w);                    \
          const int c0 = 2 * sq, c1 = 2 * sq + 1, rs = row & 7;              \
          *(bf16x8*)&lds[BUF][row * 64 + ((c0 ^ rs) << 3)] = lo;             \
          *(bf16x8*)&lds[BUF][row * 64 + ((c1 ^ rs) << 3)] = hi;             \
      } }

    LOADC(0)
    WRITEC(0)
    __syncthreads();

    #pragma unroll
    for (int c = 0; c < 4; ++c) {
        if (c < 3) LOADC(c + 1)                     // issue next-chunk loads early
        // ---- MFMA on buffer c&1
        #pragma unroll
        for (int ks = 0; ks < 2; ++ks) {
            #pragma unroll
            for (int mt = 0; mt < MT; ++mt) {
                const int row = wm * (MT * 16) + mt * 16 + l16;
                const int ch  = ks * 4 + lq;
                bf16x8 af = *(const bf16x8*)
                    &lds[c & 1][row * 64 + ((ch ^ (row & 7)) << 3)];
                acc[mt][0] = __builtin_amdgcn_mfma_f32_16x16x32_bf16(
                    af, wf[0][c * 2 + ks], acc[mt][0], 0, 0, 0);
                acc[mt][1] = __builtin_amdgcn_mfma_f32_16x16x32_bf16(
                    af, wf[1][c * 2 + ks], acc[mt][1], 0, 0, 0);
            }
        }
        if (c < 3) {
            WRITEC((c + 1) & 1)                     // write-late into other buffer
            __syncthreads();
        }
    }
#undef LOADC
#undef WRITEC

    // ---- epilogue: C(m,n): n = lane&15, m = (lane>>4)*4 + j
    #pragma unroll
    for (int mt = 0; mt < MT; ++mt) {
        const long row0 = rowbase + wm * (MT * 16) + mt * 16 + lq * 4;
        #pragma unroll
        for (int nt = 0; nt < 2; ++nt) {
            const int col = wn * 32 + nt * 16 + l16;
            #pragma unroll
            for (int j = 0; j < 4; ++j)
                y[(row0 + j) * 64 + col] = acc[mt][nt][j];
        }
    }
}

// ------------------------------------------------------------------
// Projection (unchanged from round 1)
// ------------------------------------------------------------------
template<int GS, int CG, int ROUNDS>
__global__ __launch_bounds__(256) void proj_kernel(
    const float* __restrict__ y,       // [B*N][64]
    const float* __restrict__ coords,  // [2][N]
    const int*   __restrict__ nh,      // [N][8]
    const float* __restrict__ oc,      // [2][B][N0]
    const float* __restrict__ sig_p,
    const float* __restrict__ kap_p,
    float* __restrict__ out,           // [B][N0][64]
    int N, int N0)
{
    constexpr int B = 2;
    static_assert(CG * GS == ROUNDS * 8, "slot layout");
    __shared__ float wlds[4][ROUNDS * 64];

    const int wslot = threadIdx.x >> 6;
    const int lane  = threadIdx.x & 63;
    const int wave  = (blockIdx.x << 2) + wslot;
    const int gpb   = N / CG;
    const int b     = wave / gpb;
    const int g0    = (wave - b * gpb) * CG;

    const float sigma  = *sig_p;
    const float kappa  = *kap_p;
    const float inv2s2 = 1.0f / (2.0f * sigma * sigma);

    const int j  = lane & 7;
    const int pp = lane >> 3;

    #pragma unroll
    for (int r = 0; r < ROUNDS; ++r) {
        const int pidx = r * 8 + pp;
        const int q = pidx / GS;
        const int p = pidx - q * GS;
        const int g = g0 + q;
        const int idx = nh[g * 8 + j];
        const float clon = coords[idx];
        const float clat = coords[N + idx];
        const int n = g * GS + p;
        const float olon = oc[(long)b * N0 + n];
        const float olat = oc[(long)(B + b) * N0 + n];

        float dlon = olon - clon;
        float t = (dlon + PI_F) * INV_TWO_PI_F;
        t -= floorf(t);
        dlon = t * TWO_PI_F - PI_F;
        const float dlat = olat - clat;

        float logw = -(dlat * dlat + dlon * dlon) * inv2s2
                   + kappa * (cosf(dlon) - 1.0f);

        float m = logw;
        m = fmaxf(m, __shfl_xor(m, 1));
        m = fmaxf(m, __shfl_xor(m, 2));
        m = fmaxf(m, __shfl_xor(m, 4));
        float e = expf(logw - m);
        float s = e;
        s += __shfl_xor(s, 1);
        s += __shfl_xor(s, 2);
        s += __shfl_xor(s, 4);
        wlds[wslot][r * 64 + lane] = e / s;
    }

    __syncthreads();

    const int d = lane;
    const float* yb = y + (long)b * N * 64 + d;
    #pragma unroll
    for (int pidx = 0; pidx < CG * GS; ++pidx) {
        const int q = pidx / GS;
        const int p = pidx - q * GS;
        const int g = g0 + q;
        const int* nhg = nh + g * 8;
        const float* wrow = &wlds[wslot][pidx * 8];
        float a = 0.0f;
        #pragma unroll
        for (int jj = 0; jj < 8; ++jj)
            a = fmaf(wrow[jj], yb[(long)nhg[jj] * 64], a);
        const int n = g * GS + p;
        out[((long)b * N0 + n) * 64 + d] = a;
    }
}

// ------------------------------------------------------------------
extern "C" void kernel_launch(void* const* d_in, const int* in_sizes, int n_in,
                              void* d_out, int out_size, void* d_ws, size_t ws_size,
                              hipStream_t stream)
{
    const float* x0   = (const float*)d_in[0];
    const float* x1   = (const float*)d_in[1];
    const float* x2   = (const float*)d_in[2];
    const float* W0   = (const float*)d_in[3];
    const float* W1   = (const float*)d_in[4];
    const float* W2   = (const float*)d_in[5];
    const float* sig0 = (const float*)d_in[6];
    const float* sig1 = (const float*)d_in[7];
    const float* sig2 = (const float*)d_in[8];
    const float* kap0 = (const float*)d_in[9];
    const float* kap1 = (const float*)d_in[10];
    const float* kap2 = (const float*)d_in[11];
    const float* c0   = (const float*)d_in[12];
    const float* c1   = (const float*)d_in[13];
    const float* c2   = (const float*)d_in[14];
    const int*   nh0  = (const int*)d_in[15];
    const int*   nh1  = (const int*)d_in[16];
    const int*   nh2  = (const int*)d_in[17];
    const float* oc   = (const float*)d_in[18];

    float* out = (float*)d_out;
    const size_t SLICE = (size_t)2 * 65536 * 64;
    float* ystage = out + 2 * SLICE;   // staged y0/y1 (slice 2 written last)
    float* y2     = (float*)d_ws;

    // ---- level 0: rows=131072, tile M=128 -> 1024 blocks
    gemm_mfma<4><<<131072 / 128, 256, 0, stream>>>(x0, W0, ystage);
    proj_kernel<1, 8, 1><<<(2 * 65536 / 8) / 4, 256, 0, stream>>>(
        ystage, c0, nh0, oc, sig0, kap0, out + 0 * SLICE, 65536, 65536);

    // ---- level 1: rows=32768, tile M=128 -> 256 blocks
    gemm_mfma<4><<<32768 / 128, 256, 0, stream>>>(x1, W1, ystage);
    proj_kernel<4, 2, 1><<<(2 * 16384 / 2) / 4, 256, 0, stream>>>(
        ystage, c1, nh1, oc, sig1, kap1, out + 1 * SLICE, 16384, 65536);

    // ---- level 2: rows=8192, tile M=64 -> 128 blocks
    gemm_mfma<2><<<8192 / 64, 256, 0, stream>>>(x2, W2, y2);
    proj_kernel<16, 1, 2><<<(2 * 4096 / 1) / 4, 256, 0, stream>>>(
        y2, c2, nh2, oc, sig2, kap2, out + 2 * SLICE, 4096, 65536);
}

// Round 5
// 123.889 us; speedup vs baseline: 3.7491x; 1.0728x over previous
//
#include <hip/hip_runtime.h>
#include <math.h>

#define PI_F        3.14159265358979323846f
#define TWO_PI_F    6.2831853071795864769f
#define INV_TWO_PI_F 0.15915494309189533577f

typedef __attribute__((ext_vector_type(8))) short bf16x8;
typedef __attribute__((ext_vector_type(4))) float f32x4;

__device__ inline short f2bf(float f) {
    unsigned u = __builtin_bit_cast(unsigned, f);
    unsigned r = (u + 0x7FFFu + ((u >> 16) & 1u)) >> 16;
    return (short)r;
}

// ------------------------------------------------------------------
// bf16-MFMA GEMM body: y[r][c] = sum_k x[r][k]*W[c][k], K=256, Do=64.
// 256 thr (2x2 waves), tile 128 rows x 64 cols, BK=64, double-buffered
// swizzled LDS for x; W-frags in registers.
// ------------------------------------------------------------------
__device__ __forceinline__ void gemm_body(
    int bid, short (*lds)[128 * 64],
    const float* __restrict__ x, const float* __restrict__ W,
    float* __restrict__ y)
{
    constexpr int MT = 4;

    const int tid  = threadIdx.x;
    const int lane = tid & 63;
    const int w    = tid >> 6;
    const int wm   = w >> 1;
    const int wn   = w & 1;
    const int l16  = lane & 15;
    const int lq   = lane >> 4;
    const long rowbase = (long)bid * 128;

    // ---- W fragments -> registers: wf[n-tile][k-slice(32)]
    bf16x8 wf[2][8];
    #pragma unroll
    for (int nt = 0; nt < 2; ++nt) {
        const int col = wn * 32 + nt * 16 + l16;
        const float* wp = W + (long)col * 256 + lq * 8;
        #pragma unroll
        for (int ks = 0; ks < 8; ++ks) {
            f32x4 a = *(const f32x4*)(wp + ks * 32);
            f32x4 b = *(const f32x4*)(wp + ks * 32 + 4);
            bf16x8 f;
            f[0]=f2bf(a.x); f[1]=f2bf(a.y); f[2]=f2bf(a.z); f[3]=f2bf(a.w);
            f[4]=f2bf(b.x); f[5]=f2bf(b.y); f[6]=f2bf(b.z); f[7]=f2bf(b.w);
            wf[nt][ks] = f;
        }
    }

    f32x4 acc[MT][2];
    #pragma unroll
    for (int mt = 0; mt < MT; ++mt)
        #pragma unroll
        for (int nt = 0; nt < 2; ++nt)
            acc[mt][nt] = f32x4{0.f, 0.f, 0.f, 0.f};

    const int srow = tid >> 2;               // 0..63
    const int sq   = tid & 3;                // 16-float k-segment

    f32x4 st[2][4];

#define LOADC(CH)                                                            \
    { _Pragma("unroll")                                                      \
      for (int s = 0; s < 2; ++s) {                                          \
          const float* xp = x + (rowbase + s * 64 + srow) * 256              \
                              + (CH) * 64 + sq * 16;                         \
          _Pragma("unroll")                                                  \
          for (int q = 0; q < 4; ++q) st[s][q] = *(const f32x4*)(xp + q*4);  \
      } }

#define WRITEC(BUF)                                                          \
    { _Pragma("unroll")                                                      \
      for (int s = 0; s < 2; ++s) {                                          \
          const int row = s * 64 + srow;                                     \
          bf16x8 lo, hi;                                                     \
          lo[0]=f2bf(st[s][0].x); lo[1]=f2bf(st[s][0].y);                    \
          lo[2]=f2bf(st[s][0].z); lo[3]=f2bf(st[s][0].w);                    \
          lo[4]=f2bf(st[s][1].x); lo[5]=f2bf(st[s][1].y);                    \
          lo[6]=f2bf(st[s][1].z); lo[7]=f2bf(st[s][1].w);                    \
          hi[0]=f2bf(st[s][2].x); hi[1]=f2bf(st[s][2].y);                    \
          hi[2]=f2bf(st[s][2].z); hi[3]=f2bf(st[s][2].w);                    \
          hi[4]=f2bf(st[s][3].x); hi[5]=f2bf(st[s][3].y);                    \
          hi[6]=f2bf(st[s][3].z); hi[7]=f2bf(st[s][3].w);                    \
          const int c0 = 2 * sq, c1 = 2 * sq + 1, rs = row & 7;              \
          *(bf16x8*)&lds[BUF][row * 64 + ((c0 ^ rs) << 3)] = lo;             \
          *(bf16x8*)&lds[BUF][row * 64 + ((c1 ^ rs) << 3)] = hi;             \
      } }

    LOADC(0)
    WRITEC(0)
    __syncthreads();

    #pragma unroll
    for (int c = 0; c < 4; ++c) {
        if (c < 3) LOADC(c + 1)                     // issue next-chunk loads early
        #pragma unroll
        for (int ks = 0; ks < 2; ++ks) {
            #pragma unroll
            for (int mt = 0; mt < MT; ++mt) {
                const int row = wm * (MT * 16) + mt * 16 + l16;
                const int ch  = ks * 4 + lq;
                bf16x8 af = *(const bf16x8*)
                    &lds[c & 1][row * 64 + ((ch ^ (row & 7)) << 3)];
                acc[mt][0] = __builtin_amdgcn_mfma_f32_16x16x32_bf16(
                    af, wf[0][c * 2 + ks], acc[mt][0], 0, 0, 0);
                acc[mt][1] = __builtin_amdgcn_mfma_f32_16x16x32_bf16(
                    af, wf[1][c * 2 + ks], acc[mt][1], 0, 0, 0);
            }
        }
        if (c < 3) {
            WRITEC((c + 1) & 1)                     // write-late into other buffer
            __syncthreads();
        }
    }
#undef LOADC
#undef WRITEC

    // ---- epilogue: C(m,n): n = lane&15, m = (lane>>4)*4 + j
    #pragma unroll
    for (int mt = 0; mt < MT; ++mt) {
        const long row0 = rowbase + wm * (MT * 16) + mt * 16 + lq * 4;
        #pragma unroll
        for (int nt = 0; nt < 2; ++nt) {
            const int col = wn * 32 + nt * 16 + l16;
            #pragma unroll
            for (int j = 0; j < 4; ++j)
                y[(row0 + j) * 64 + col] = acc[mt][nt][j];
        }
    }
}

// Fused GEMM over the three levels: blocks [0,1024) L0, [1024,1280) L1,
// [1280,1344) L2. All levels use the 128-row tile.
__global__ __launch_bounds__(256) void gemm_fused(
    const float* __restrict__ x0, const float* __restrict__ x1,
    const float* __restrict__ x2,
    const float* __restrict__ W0, const float* __restrict__ W1,
    const float* __restrict__ W2,
    float* __restrict__ y0, float* __restrict__ y1, float* __restrict__ y2)
{
    __shared__ short lds[2][128 * 64];
    const int b = blockIdx.x;
    if (b < 1024)       gemm_body(b,        lds, x0, W0, y0);
    else if (b < 1280)  gemm_body(b - 1024, lds, x1, W1, y1);
    else                gemm_body(b - 1280, lds, x2, W2, y2);
}

// ------------------------------------------------------------------
// Projection body: per group g, neighbors nh[g][0..7]:
//   logw[p][j] = -(dlat^2+dlon_w^2)/(2 sigma^2) + kappa*(cos(dlon_w)-1)
//   w = softmax_j(logw);  out[n=g*GS+p][d] = sum_j w[p][j]*y[nh[g][j]][d]
// One wave handles CG groups (CG*GS == ROUNDS*8 point-slots).
// ------------------------------------------------------------------
template<int GS, int CG, int ROUNDS>
__device__ __forceinline__ void proj_body(
    int bid, float (*wlds)[128],
    const float* __restrict__ y,       // [B*N][64]
    const float* __restrict__ coords,  // [2][N]
    const int*   __restrict__ nh,      // [N][8]
    const float* __restrict__ oc,      // [2][B][N0]
    const float* __restrict__ sig_p,
    const float* __restrict__ kap_p,
    float* __restrict__ out,           // [B][N0][64]
    int N, int N0)
{
    constexpr int B = 2;
    static_assert(CG * GS == ROUNDS * 8, "slot layout");

    const int wslot = threadIdx.x >> 6;
    const int lane  = threadIdx.x & 63;
    const int wave  = (bid << 2) + wslot;
    const int gpb   = N / CG;
    const int b     = wave / gpb;
    const int g0    = (wave - b * gpb) * CG;

    const float sigma  = *sig_p;
    const float kappa  = *kap_p;
    const float inv2s2 = 1.0f / (2.0f * sigma * sigma);

    const int j  = lane & 7;
    const int pp = lane >> 3;

    #pragma unroll
    for (int r = 0; r < ROUNDS; ++r) {
        const int pidx = r * 8 + pp;
        const int q = pidx / GS;
        const int p = pidx - q * GS;
        const int g = g0 + q;
        const int idx = nh[g * 8 + j];
        const float clon = coords[idx];
        const float clat = coords[N + idx];
        const int n = g * GS + p;
        const float olon = oc[(long)b * N0 + n];
        const float olat = oc[(long)(B + b) * N0 + n];

        float dlon = olon - clon;
        float t = (dlon + PI_F) * INV_TWO_PI_F;   // floor-mod wrap to [-pi, pi)
        t -= floorf(t);
        dlon = t * TWO_PI_F - PI_F;
        const float dlat = olat - clat;

        float logw = -(dlat * dlat + dlon * dlon) * inv2s2
                   + kappa * (cosf(dlon) - 1.0f);

        float m = logw;
        m = fmaxf(m, __shfl_xor(m, 1));
        m = fmaxf(m, __shfl_xor(m, 2));
        m = fmaxf(m, __shfl_xor(m, 4));
        float e = expf(logw - m);
        float s = e;
        s += __shfl_xor(s, 1);
        s += __shfl_xor(s, 2);
        s += __shfl_xor(s, 4);
        wlds[wslot][r * 64 + lane] = e / s;
    }

    __syncthreads();

    const int d = lane;
    const float* yb = y + (long)b * N * 64 + d;
    #pragma unroll
    for (int pidx = 0; pidx < CG * GS; ++pidx) {
        const int q = pidx / GS;
        const int p = pidx - q * GS;
        const int g = g0 + q;
        const int* nhg = nh + g * 8;
        const float* wrow = &wlds[wslot][(pidx >> 3) * 64 + (pidx & 7) * 8];
        float a = 0.0f;
        #pragma unroll
        for (int jj = 0; jj < 8; ++jj)
            a = fmaf(wrow[jj], yb[(long)nhg[jj] * 64], a);
        const int n = g * GS + p;
        out[((long)b * N0 + n) * 64 + d] = a;
    }
}

// Fused projection: blocks [0,4096) L0, [4096,8192) L1, [8192,10240) L2.
__global__ __launch_bounds__(256) void proj_fused(
    const float* __restrict__ y0, const float* __restrict__ y1,
    const float* __restrict__ y2,
    const float* __restrict__ c0, const float* __restrict__ c1,
    const float* __restrict__ c2,
    const int* __restrict__ nh0, const int* __restrict__ nh1,
    const int* __restrict__ nh2,
    const float* __restrict__ oc,
    const float* __restrict__ sig0, const float* __restrict__ sig1,
    const float* __restrict__ sig2,
    const float* __restrict__ kap0, const float* __restrict__ kap1,
    const float* __restrict__ kap2,
    float* __restrict__ out)
{
    __shared__ float wlds[4][128];
    const size_t SLICE = (size_t)2 * 65536 * 64;
    const int b = blockIdx.x;
    if (b < 4096)
        proj_body<1, 8, 1>(b, wlds, y0, c0, nh0, oc, sig0, kap0,
                           out, 65536, 65536);
    else if (b < 8192)
        proj_body<4, 2, 1>(b - 4096, wlds, y1, c1, nh1, oc, sig1, kap1,
                           out + SLICE, 16384, 65536);
    else
        proj_body<16, 1, 2>(b - 8192, wlds, y2, c2, nh2, oc, sig2, kap2,
                            out + 2 * SLICE, 4096, 65536);
}

// ------------------------------------------------------------------
extern "C" void kernel_launch(void* const* d_in, const int* in_sizes, int n_in,
                              void* d_out, int out_size, void* d_ws, size_t ws_size,
                              hipStream_t stream)
{
    const float* x0   = (const float*)d_in[0];
    const float* x1   = (const float*)d_in[1];
    const float* x2   = (const float*)d_in[2];
    const float* W0   = (const float*)d_in[3];
    const float* W1   = (const float*)d_in[4];
    const float* W2   = (const float*)d_in[5];
    const float* sig0 = (const float*)d_in[6];
    const float* sig1 = (const float*)d_in[7];
    const float* sig2 = (const float*)d_in[8];
    const float* kap0 = (const float*)d_in[9];
    const float* kap1 = (const float*)d_in[10];
    const float* kap2 = (const float*)d_in[11];
    const float* c0   = (const float*)d_in[12];
    const float* c1   = (const float*)d_in[13];
    const float* c2   = (const float*)d_in[14];
    const int*   nh0  = (const int*)d_in[15];
    const int*   nh1  = (const int*)d_in[16];
    const int*   nh2  = (const int*)d_in[17];
    const float* oc   = (const float*)d_in[18];

    float* out = (float*)d_out;
    // y staging entirely in d_ws (ws is ~512 MiB; we need 44 MB)
    float* y0 = (float*)d_ws;
    float* y1 = y0 + (size_t)2 * 65536 * 64;
    float* y2 = y1 + (size_t)2 * 16384 * 64;

    gemm_fused<<<1344, 256, 0, stream>>>(x0, x1, x2, W0, W1, W2, y0, y1, y2);
    proj_fused<<<10240, 256, 0, stream>>>(y0, y1, y2, c0, c1, c2,
                                          nh0, nh1, nh2, oc,
                                          sig0, sig1, sig2,
                                          kap0, kap1, kap2, out);
}

// Round 6
// 120.308 us; speedup vs baseline: 3.8607x; 1.0298x over previous
//
#include <hip/hip_runtime.h>
#include <math.h>

#define PI_F        3.14159265358979323846f
#define TWO_PI_F    6.2831853071795864769f
#define INV_TWO_PI_F 0.15915494309189533577f

typedef __attribute__((ext_vector_type(8))) short  bf16x8;
typedef __attribute__((ext_vector_type(8))) __bf16 bf16v8;
typedef __attribute__((ext_vector_type(4))) float  f32x4;

__device__ __forceinline__ bf16x8 cvt8(f32x4 a, f32x4 b) {
    bf16v8 v;
    v[0] = (__bf16)a.x; v[1] = (__bf16)a.y; v[2] = (__bf16)a.z; v[3] = (__bf16)a.w;
    v[4] = (__bf16)b.x; v[5] = (__bf16)b.y; v[6] = (__bf16)b.z; v[7] = (__bf16)b.w;
    return __builtin_bit_cast(bf16x8, v);
}

// ------------------------------------------------------------------
// bf16-MFMA GEMM: y[r][c] = sum_k x[r][k]*W[c][k], K=256, Do=64.
// 256 thr = 4 waves; wave w owns cols [w*16, w*16+16), all 64 tile rows.
// x staged f32 -> LDS via global_load_lds (BK=32, double-buffered,
// source-side XOR swizzle); bf16 conversion at fragment-read time.
// W-frags (16 cols/wave) in registers, converted once.
// MFMA 16x16x32: A(m,k): lane=(k>>3)*16+m, slots k&7.
//                B(k,n): lane=(k>>3)*16+n -> W[n][k..k+7] row-major.
//                C(m,n): n=lane&15, m=(lane>>4)*4+reg.
// ------------------------------------------------------------------
__device__ __forceinline__ void gemm_body(
    int bid, float (*lds)[64 * 32],
    const float* __restrict__ x, const float* __restrict__ W,
    float* __restrict__ y)
{
    const int tid  = threadIdx.x;
    const int lane = tid & 63;
    const int w    = tid >> 6;
    const int l16  = lane & 15;
    const int lq   = lane >> 4;
    const long rowbase = (long)bid * 64;

    // ---- W fragments: wave w covers cols w*16 + l16; wf[ks] = k-slice ks*32
    bf16x8 wf[8];
    {
        const int col = w * 16 + l16;
        const float* wp = W + (long)col * 256 + lq * 8;
        #pragma unroll
        for (int ks = 0; ks < 8; ++ks) {
            f32x4 a = *(const f32x4*)(wp + ks * 32);
            f32x4 b = *(const f32x4*)(wp + ks * 32 + 4);
            wf[ks] = cvt8(a, b);
        }
    }

    f32x4 acc[4];
    #pragma unroll
    for (int mt = 0; mt < 4; ++mt) acc[mt] = f32x4{0.f, 0.f, 0.f, 0.f};

    // staging geometry: chunk = 64 rows x 32 f32 (128 B/row) = 8 KB,
    // 8 wave-issues of 1 KB. Lane l covers row seg*8 + (l>>3), 16B col l&7.
    // Source is pre-swizzled so LDS[row][c] holds global seg c ^ (row&7).
    const int csrc = (lane & 7) ^ (lane >> 3);   // row&7 == lane>>3 (seg%8==0)

#define STAGE(BUF, CH)                                                       \
    { _Pragma("unroll")                                                      \
      for (int j = 0; j < 2; ++j) {                                          \
          const int seg = w * 2 + j;                                         \
          const float* src = x + (rowbase + seg * 8 + (lane >> 3)) * 256     \
                               + (CH) * 32 + csrc * 4;                       \
          __builtin_amdgcn_global_load_lds(                                  \
              (const __attribute__((address_space(1))) unsigned int*)src,    \
              (__attribute__((address_space(3))) unsigned int*)              \
                  &lds[BUF][seg * 256],                                      \
              16, 0, 0);                                                     \
      } }

    STAGE(0, 0)
    __syncthreads();

    #pragma unroll
    for (int c = 0; c < 8; ++c) {
        if (c < 7) STAGE((c + 1) & 1, c + 1)       // prefetch next chunk
        const float* lb = lds[c & 1];
        #pragma unroll
        for (int mt = 0; mt < 4; ++mt) {
            const int rl = mt * 16 + l16;
            const char* lp = (const char*)(lb + rl * 32);
            f32x4 a0 = *(const f32x4*)(lp + ((((lq * 2))     ^ (l16 & 7)) << 4));
            f32x4 a1 = *(const f32x4*)(lp + ((((lq * 2) | 1) ^ (l16 & 7)) << 4));
            acc[mt] = __builtin_amdgcn_mfma_f32_16x16x32_bf16(
                cvt8(a0, a1), wf[c], acc[mt], 0, 0, 0);
        }
        if (c < 7) __syncthreads();
    }
#undef STAGE

    // ---- epilogue: C(m,n): n = lane&15, m = (lane>>4)*4 + j
    #pragma unroll
    for (int mt = 0; mt < 4; ++mt) {
        const long r0 = rowbase + mt * 16 + lq * 4;
        const int col = w * 16 + l16;
        #pragma unroll
        for (int j = 0; j < 4; ++j)
            y[(r0 + j) * 64 + col] = acc[mt][j];
    }
}

// Fused GEMM: blocks [0,2048) L0, [2048,2560) L1, [2560,2688) L2 (64-row tiles)
__global__ __launch_bounds__(256) void gemm_fused(
    const float* __restrict__ x0, const float* __restrict__ x1,
    const float* __restrict__ x2,
    const float* __restrict__ W0, const float* __restrict__ W1,
    const float* __restrict__ W2,
    float* __restrict__ y0, float* __restrict__ y1, float* __restrict__ y2)
{
    __shared__ float lds[2][64 * 32];
    const int b = blockIdx.x;
    if (b < 2048)       gemm_body(b,        lds, x0, W0, y0);
    else if (b < 2560)  gemm_body(b - 2048, lds, x1, W1, y1);
    else                gemm_body(b - 2560, lds, x2, W2, y2);
}

// ------------------------------------------------------------------
// Projection body (unchanged): per group g, neighbors nh[g][0..7]:
//   logw[p][j] = -(dlat^2+dlon_w^2)/(2 sigma^2) + kappa*(cos(dlon_w)-1)
//   w = softmax_j(logw);  out[n=g*GS+p][d] = sum_j w[p][j]*y[nh[g][j]][d]
// ------------------------------------------------------------------
template<int GS, int CG, int ROUNDS>
__device__ __forceinline__ void proj_body(
    int bid, float (*wlds)[128],
    const float* __restrict__ y,       // [B*N][64]
    const float* __restrict__ coords,  // [2][N]
    const int*   __restrict__ nh,      // [N][8]
    const float* __restrict__ oc,      // [2][B][N0]
    const float* __restrict__ sig_p,
    const float* __restrict__ kap_p,
    float* __restrict__ out,           // [B][N0][64]
    int N, int N0)
{
    constexpr int B = 2;
    static_assert(CG * GS == ROUNDS * 8, "slot layout");

    const int wslot = threadIdx.x >> 6;
    const int lane  = threadIdx.x & 63;
    const int wave  = (bid << 2) + wslot;
    const int gpb   = N / CG;
    const int b     = wave / gpb;
    const int g0    = (wave - b * gpb) * CG;

    const float sigma  = *sig_p;
    const float kappa  = *kap_p;
    const float inv2s2 = 1.0f / (2.0f * sigma * sigma);

    const int j  = lane & 7;
    const int pp = lane >> 3;

    #pragma unroll
    for (int r = 0; r < ROUNDS; ++r) {
        const int pidx = r * 8 + pp;
        const int q = pidx / GS;
        const int p = pidx - q * GS;
        const int g = g0 + q;
        const int idx = nh[g * 8 + j];
        const float clon = coords[idx];
        const float clat = coords[N + idx];
        const int n = g * GS + p;
        const float olon = oc[(long)b * N0 + n];
        const float olat = oc[(long)(B + b) * N0 + n];

        float dlon = olon - clon;
        float t = (dlon + PI_F) * INV_TWO_PI_F;   // floor-mod wrap to [-pi, pi)
        t -= floorf(t);
        dlon = t * TWO_PI_F - PI_F;
        const float dlat = olat - clat;

        float logw = -(dlat * dlat + dlon * dlon) * inv2s2
                   + kappa * (cosf(dlon) - 1.0f);

        float m = logw;
        m = fmaxf(m, __shfl_xor(m, 1));
        m = fmaxf(m, __shfl_xor(m, 2));
        m = fmaxf(m, __shfl_xor(m, 4));
        float e = expf(logw - m);
        float s = e;
        s += __shfl_xor(s, 1);
        s += __shfl_xor(s, 2);
        s += __shfl_xor(s, 4);
        wlds[wslot][r * 64 + lane] = e / s;
    }

    __syncthreads();

    const int d = lane;
    const float* yb = y + (long)b * N * 64 + d;
    #pragma unroll
    for (int pidx = 0; pidx < CG * GS; ++pidx) {
        const int q = pidx / GS;
        const int p = pidx - q * GS;
        const int g = g0 + q;
        const int* nhg = nh + g * 8;
        const float* wrow = &wlds[wslot][(pidx >> 3) * 64 + (pidx & 7) * 8];
        float a = 0.0f;
        #pragma unroll
        for (int jj = 0; jj < 8; ++jj)
            a = fmaf(wrow[jj], yb[(long)nhg[jj] * 64], a);
        const int n = g * GS + p;
        out[((long)b * N0 + n) * 64 + d] = a;
    }
}

// Fused projection: blocks [0,4096) L0, [4096,8192) L1, [8192,10240) L2.
__global__ __launch_bounds__(256) void proj_fused(
    const float* __restrict__ y0, const float* __restrict__ y1,
    const float* __restrict__ y2,
    const float* __restrict__ c0, const float* __restrict__ c1,
    const float* __restrict__ c2,
    const int* __restrict__ nh0, const int* __restrict__ nh1,
    const int* __restrict__ nh2,
    const float* __restrict__ oc,
    const float* __restrict__ sig0, const float* __restrict__ sig1,
    const float* __restrict__ sig2,
    const float* __restrict__ kap0, const float* __restrict__ kap1,
    const float* __restrict__ kap2,
    float* __restrict__ out)
{
    __shared__ float wlds[4][128];
    const size_t SLICE = (size_t)2 * 65536 * 64;
    const int b = blockIdx.x;
    if (b < 4096)
        proj_body<1, 8, 1>(b, wlds, y0, c0, nh0, oc, sig0, kap0,
                           out, 65536, 65536);
    else if (b < 8192)
        proj_body<4, 2, 1>(b - 4096, wlds, y1, c1, nh1, oc, sig1, kap1,
                           out + SLICE, 16384, 65536);
    else
        proj_body<16, 1, 2>(b - 8192, wlds, y2, c2, nh2, oc, sig2, kap2,
                            out + 2 * SLICE, 4096, 65536);
}

// ------------------------------------------------------------------
extern "C" void kernel_launch(void* const* d_in, const int* in_sizes, int n_in,
                              void* d_out, int out_size, void* d_ws, size_t ws_size,
                              hipStream_t stream)
{
    const float* x0   = (const float*)d_in[0];
    const float* x1   = (const float*)d_in[1];
    const float* x2   = (const float*)d_in[2];
    const float* W0   = (const float*)d_in[3];
    const float* W1   = (const float*)d_in[4];
    const float* W2   = (const float*)d_in[5];
    const float* sig0 = (const float*)d_in[6];
    const float* sig1 = (const float*)d_in[7];
    const float* sig2 = (const float*)d_in[8];
    const float* kap0 = (const float*)d_in[9];
    const float* kap1 = (const float*)d_in[10];
    const float* kap2 = (const float*)d_in[11];
    const float* c0   = (const float*)d_in[12];
    const float* c1   = (const float*)d_in[13];
    const float* c2   = (const float*)d_in[14];
    const int*   nh0  = (const int*)d_in[15];
    const int*   nh1  = (const int*)d_in[16];
    const int*   nh2  = (const int*)d_in[17];
    const float* oc   = (const float*)d_in[18];

    float* out = (float*)d_out;
    // y staging entirely in d_ws (ws is ~512 MiB; we need 44 MB)
    float* y0 = (float*)d_ws;
    float* y1 = y0 + (size_t)2 * 65536 * 64;
    float* y2 = y1 + (size_t)2 * 16384 * 64;

    gemm_fused<<<2688, 256, 0, stream>>>(x0, x1, x2, W0, W1, W2, y0, y1, y2);
    proj_fused<<<10240, 256, 0, stream>>>(y0, y1, y2, c0, c1, c2,
                                          nh0, nh1, nh2, oc,
                                          sig0, sig1, sig2,
                                          kap0, kap1, kap2, out);
}

// Round 7
// 116.849 us; speedup vs baseline: 3.9750x; 1.0296x over previous
//
#include <hip/hip_runtime.h>
#include <math.h>

#define PI_F        3.14159265358979323846f
#define TWO_PI_F    6.2831853071795864769f
#define INV_TWO_PI_F 0.15915494309189533577f

typedef __attribute__((ext_vector_type(8))) short  bf16x8;
typedef __attribute__((ext_vector_type(8))) __bf16 bf16v8;
typedef __attribute__((ext_vector_type(4))) float  f32x4;

__device__ __forceinline__ bf16x8 cvt8(f32x4 a, f32x4 b) {
    bf16v8 v;
    v[0] = (__bf16)a.x; v[1] = (__bf16)a.y; v[2] = (__bf16)a.z; v[3] = (__bf16)a.w;
    v[4] = (__bf16)b.x; v[5] = (__bf16)b.y; v[6] = (__bf16)b.z; v[7] = (__bf16)b.w;
    return __builtin_bit_cast(bf16x8, v);
}

// ------------------------------------------------------------------
// bf16-MFMA GEMM: y[r][c] = sum_k x[r][k]*W[c][k], K=256, Do=64.
// 256 thr = 4 waves; wave w owns cols [w*16, w*16+16), all 64 tile rows.
// Whole 64-row x-tile (64KB f32) staged to LDS in ONE burst of 16
// global_load_lds issues per thread (Little's law: ~128KB in flight/CU),
// single barrier, then 32 MFMA/wave. Source-side 16B-chunk XOR swizzle
// (chunk ^= row&7) keeps ds_read conflicts at 2-way.
// MFMA 16x16x32: A(m,k): lane=(k>>3)*16+m, slots k&7.
//                B(k,n): lane=(k>>3)*16+n -> W[n][k..k+7] row-major.
//                C(m,n): n=lane&15, m=(lane>>4)*4+reg.
// ------------------------------------------------------------------
__device__ __forceinline__ void gemm_body(
    int bid, float* lds,               // [64][256] f32, chunk-swizzled
    const float* __restrict__ x, const float* __restrict__ W,
    float* __restrict__ y)
{
    const int tid  = threadIdx.x;
    const int lane = tid & 63;
    const int w    = tid >> 6;
    const int l16  = lane & 15;
    const int lq   = lane >> 4;
    const long rowbase = (long)bid * 64;

    // ---- stage entire x-tile: wave w stages rows w*16 .. w*16+15.
    // Issue i -> LDS row r (lane l writes chunk l linearly); global source
    // chunk = l ^ (r&7)  (both-sides swizzle, rule #21).
    #pragma unroll
    for (int i = 0; i < 16; ++i) {
        const int r = w * 16 + i;
        const float* src = x + (rowbase + r) * 256 + ((lane ^ (r & 7)) << 2);
        __builtin_amdgcn_global_load_lds(
            (const __attribute__((address_space(1))) unsigned int*)src,
            (__attribute__((address_space(3))) unsigned int*)(lds + r * 256),
            16, 0, 0);
    }

    // ---- W fragments while loads fly: wave w covers col w*16 + l16
    bf16x8 wf[8];
    {
        const int col = w * 16 + l16;
        const float* wp = W + (long)col * 256 + lq * 8;
        #pragma unroll
        for (int ks = 0; ks < 8; ++ks)
            wf[ks] = cvt8(*(const f32x4*)(wp + ks * 32),
                          *(const f32x4*)(wp + ks * 32 + 4));
    }

    f32x4 acc[4];
    #pragma unroll
    for (int mt = 0; mt < 4; ++mt) acc[mt] = f32x4{0.f, 0.f, 0.f, 0.f};

    __syncthreads();

    // ---- all MFMAs from LDS (4 independent acc chains)
    #pragma unroll
    for (int ks = 0; ks < 8; ++ks) {
        #pragma unroll
        for (int mt = 0; mt < 4; ++mt) {
            const int r  = mt * 16 + l16;
            const float* lp = lds + r * 256;
            const int c0 = ks * 8 + lq * 2;
            f32x4 a0 = *(const f32x4*)(lp + (((c0)     ^ (r & 7)) << 2));
            f32x4 a1 = *(const f32x4*)(lp + (((c0 | 1) ^ (r & 7)) << 2));
            acc[mt] = __builtin_amdgcn_mfma_f32_16x16x32_bf16(
                cvt8(a0, a1), wf[ks], acc[mt], 0, 0, 0);
        }
    }

    // ---- epilogue: C(m,n): n = lane&15, m = (lane>>4)*4 + j
    #pragma unroll
    for (int mt = 0; mt < 4; ++mt) {
        const long r0 = rowbase + mt * 16 + lq * 4;
        const int col = w * 16 + l16;
        #pragma unroll
        for (int j = 0; j < 4; ++j)
            y[(r0 + j) * 64 + col] = acc[mt][j];
    }
}

// Fused GEMM: blocks [0,2048) L0, [2048,2560) L1, [2560,2688) L2 (64-row tiles)
__global__ __launch_bounds__(256) void gemm_fused(
    const float* __restrict__ x0, const float* __restrict__ x1,
    const float* __restrict__ x2,
    const float* __restrict__ W0, const float* __restrict__ W1,
    const float* __restrict__ W2,
    float* __restrict__ y0, float* __restrict__ y1, float* __restrict__ y2)
{
    __shared__ float lds[64 * 256];    // 64 KB -> 2 blocks/CU
    const int b = blockIdx.x;
    if (b < 2048)       gemm_body(b,        lds, x0, W0, y0);
    else if (b < 2560)  gemm_body(b - 2048, lds, x1, W1, y1);
    else                gemm_body(b - 2560, lds, x2, W2, y2);
}

// ------------------------------------------------------------------
// Projection body (unchanged): per group g, neighbors nh[g][0..7]:
//   logw[p][j] = -(dlat^2+dlon_w^2)/(2 sigma^2) + kappa*(cos(dlon_w)-1)
//   w = softmax_j(logw);  out[n=g*GS+p][d] = sum_j w[p][j]*y[nh[g][j]][d]
// ------------------------------------------------------------------
template<int GS, int CG, int ROUNDS>
__device__ __forceinline__ void proj_body(
    int bid, float (*wlds)[128],
    const float* __restrict__ y,       // [B*N][64]
    const float* __restrict__ coords,  // [2][N]
    const int*   __restrict__ nh,      // [N][8]
    const float* __restrict__ oc,      // [2][B][N0]
    const float* __restrict__ sig_p,
    const float* __restrict__ kap_p,
    float* __restrict__ out,           // [B][N0][64]
    int N, int N0)
{
    constexpr int B = 2;
    static_assert(CG * GS == ROUNDS * 8, "slot layout");

    const int wslot = threadIdx.x >> 6;
    const int lane  = threadIdx.x & 63;
    const int wave  = (bid << 2) + wslot;
    const int gpb   = N / CG;
    const int b     = wave / gpb;
    const int g0    = (wave - b * gpb) * CG;

    const float sigma  = *sig_p;
    const float kappa  = *kap_p;
    const float inv2s2 = 1.0f / (2.0f * sigma * sigma);

    const int j  = lane & 7;
    const int pp = lane >> 3;

    #pragma unroll
    for (int r = 0; r < ROUNDS; ++r) {
        const int pidx = r * 8 + pp;
        const int q = pidx / GS;
        const int p = pidx - q * GS;
        const int g = g0 + q;
        const int idx = nh[g * 8 + j];
        const float clon = coords[idx];
        const float clat = coords[N + idx];
        const int n = g * GS + p;
        const float olon = oc[(long)b * N0 + n];
        const float olat = oc[(long)(B + b) * N0 + n];

        float dlon = olon - clon;
        float t = (dlon + PI_F) * INV_TWO_PI_F;   // floor-mod wrap to [-pi, pi)
        t -= floorf(t);
        dlon = t * TWO_PI_F - PI_F;
        const float dlat = olat - clat;

        float logw = -(dlat * dlat + dlon * dlon) * inv2s2
                   + kappa * (cosf(dlon) - 1.0f);

        float m = logw;
        m = fmaxf(m, __shfl_xor(m, 1));
        m = fmaxf(m, __shfl_xor(m, 2));
        m = fmaxf(m, __shfl_xor(m, 4));
        float e = expf(logw - m);
        float s = e;
        s += __shfl_xor(s, 1);
        s += __shfl_xor(s, 2);
        s += __shfl_xor(s, 4);
        wlds[wslot][r * 64 + lane] = e / s;
    }

    __syncthreads();

    const int d = lane;
    const float* yb = y + (long)b * N * 64 + d;
    #pragma unroll
    for (int pidx = 0; pidx < CG * GS; ++pidx) {
        const int q = pidx / GS;
        const int p = pidx - q * GS;
        const int g = g0 + q;
        const int* nhg = nh + g * 8;
        const float* wrow = &wlds[wslot][(pidx >> 3) * 64 + (pidx & 7) * 8];
        float a = 0.0f;
        #pragma unroll
        for (int jj = 0; jj < 8; ++jj)
            a = fmaf(wrow[jj], yb[(long)nhg[jj] * 64], a);
        const int n = g * GS + p;
        out[((long)b * N0 + n) * 64 + d] = a;
    }
}

// Fused projection: blocks [0,4096) L0, [4096,8192) L1, [8192,10240) L2.
__global__ __launch_bounds__(256) void proj_fused(
    const float* __restrict__ y0, const float* __restrict__ y1,
    const float* __restrict__ y2,
    const float* __restrict__ c0, const float* __restrict__ c1,
    const float* __restrict__ c2,
    const int* __restrict__ nh0, const int* __restrict__ nh1,
    const int* __restrict__ nh2,
    const float* __restrict__ oc,
    const float* __restrict__ sig0, const float* __restrict__ sig1,
    const float* __restrict__ sig2,
    const float* __restrict__ kap0, const float* __restrict__ kap1,
    const float* __restrict__ kap2,
    float* __restrict__ out)
{
    __shared__ float wlds[4][128];
    const size_t SLICE = (size_t)2 * 65536 * 64;
    const int b = blockIdx.x;
    if (b < 4096)
        proj_body<1, 8, 1>(b, wlds, y0, c0, nh0, oc, sig0, kap0,
                           out, 65536, 65536);
    else if (b < 8192)
        proj_body<4, 2, 1>(b - 4096, wlds, y1, c1, nh1, oc, sig1, kap1,
                           out + SLICE, 16384, 65536);
    else
        proj_body<16, 1, 2>(b - 8192, wlds, y2, c2, nh2, oc, sig2, kap2,
                            out + 2 * SLICE, 4096, 65536);
}

// ------------------------------------------------------------------
extern "C" void kernel_launch(void* const* d_in, const int* in_sizes, int n_in,
                              void* d_out, int out_size, void* d_ws, size_t ws_size,
                              hipStream_t stream)
{
    const float* x0   = (const float*)d_in[0];
    const float* x1   = (const float*)d_in[1];
    const float* x2   = (const float*)d_in[2];
    const float* W0   = (const float*)d_in[3];
    const float* W1   = (const float*)d_in[4];
    const float* W2   = (const float*)d_in[5];
    const float* sig0 = (const float*)d_in[6];
    const float* sig1 = (const float*)d_in[7];
    const float* sig2 = (const float*)d_in[8];
    const float* kap0 = (const float*)d_in[9];
    const float* kap1 = (const float*)d_in[10];
    const float* kap2 = (const float*)d_in[11];
    const float* c0   = (const float*)d_in[12];
    const float* c1   = (const float*)d_in[13];
    const float* c2   = (const float*)d_in[14];
    const int*   nh0  = (const int*)d_in[15];
    const int*   nh1  = (const int*)d_in[16];
    const int*   nh2  = (const int*)d_in[17];
    const float* oc   = (const float*)d_in[18];

    float* out = (float*)d_out;
    // y staging entirely in d_ws (ws is ~512 MiB; we need 44 MB)
    float* y0 = (float*)d_ws;
    float* y1 = y0 + (size_t)2 * 65536 * 64;
    float* y2 = y1 + (size_t)2 * 16384 * 64;

    gemm_fused<<<2688, 256, 0, stream>>>(x0, x1, x2, W0, W1, W2, y0, y1, y2);
    proj_fused<<<10240, 256, 0, stream>>>(y0, y1, y2, c0, c1, c2,
                                          nh0, nh1, nh2, oc,
                                          sig0, sig1, sig2,
                                          kap0, kap1, kap2, out);
}

// Round 8
// 112.447 us; speedup vs baseline: 4.1306x; 1.0391x over previous
//
#include <hip/hip_runtime.h>
#include <math.h>

#define PI_F        3.14159265358979323846f
#define TWO_PI_F    6.2831853071795864769f
#define INV_TWO_PI_F 0.15915494309189533577f

typedef __attribute__((ext_vector_type(8))) short  bf16x8;
typedef __attribute__((ext_vector_type(8))) __bf16 bf16v8;
typedef __attribute__((ext_vector_type(4))) float  f32x4;

__device__ __forceinline__ bf16x8 cvt8(f32x4 a, f32x4 b) {
    bf16v8 v;
    v[0] = (__bf16)a.x; v[1] = (__bf16)a.y; v[2] = (__bf16)a.z; v[3] = (__bf16)a.w;
    v[4] = (__bf16)b.x; v[5] = (__bf16)b.y; v[6] = (__bf16)b.z; v[7] = (__bf16)b.w;
    return __builtin_bit_cast(bf16x8, v);
}

// ------------------------------------------------------------------
// bf16-MFMA GEMM, counted-vmcnt streaming (T3/T4): y = x (.) W^T, K=256,
// Do=64, y stored bf16. 256 thr = 4 waves; wave w owns cols [w*16,w*16+16),
// all 32 tile rows (2 m-tiles). x tile = 32 rows staged as 4 chunks of
// K=64 (chunk-major LDS [4][32][64] f32) via global_load_lds; per-chunk
// wait is s_waitcnt vmcnt((3-c)*2) — loads for later chunks NEVER drain.
// Source-side 16B-chunk XOR swizzle (col16 ^= r&7) -> 2-way ds_read.
// MFMA 16x16x32: A(m,k): lane=(k>>3)*16+m, slots k&7.
//                B(k,n): lane=(k>>3)*16+n -> W[n][k..k+7] row-major.
//                C(m,n): n=lane&15, m=(lane>>4)*4+reg.
// ------------------------------------------------------------------
__device__ __forceinline__ void gemm_body(
    int bid, float* lds,               // [4][32][64] f32, chunk-major
    const float* __restrict__ x, const float* __restrict__ W,
    __bf16* __restrict__ y)
{
    const int tid  = threadIdx.x;
    const int lane = tid & 63;
    const int w    = tid >> 6;
    const int l16  = lane & 15;
    const int lq   = lane >> 4;
    const long rowbase = (long)bid * 32;

    // ---- W fragments FIRST (these VMEM loads are oldest in vmcnt order,
    // so they retire before any chunk-wait targets them).
    bf16x8 wf[8];
    {
        const int col = w * 16 + l16;
        const float* wp = W + (long)col * 256 + lq * 8;
        #pragma unroll
        for (int ks = 0; ks < 8; ++ks)
            wf[ks] = cvt8(*(const f32x4*)(wp + ks * 32),
                          *(const f32x4*)(wp + ks * 32 + 4));
    }

    // ---- stage: 8 DMA issues/thread, chunk-major. Issue (c,h):
    // row r = w*8 + h*4 + (lane>>4), source 16B-chunk = (lane&15) ^ (r&7),
    // LDS dest = chunk c base + (w*8+h*4)*256B (+ lane*16 linear).
    #pragma unroll
    for (int c = 0; c < 4; ++c) {
        #pragma unroll
        for (int h = 0; h < 2; ++h) {
            const int r = w * 8 + h * 4 + (lane >> 4);
            const int col16 = (lane & 15) ^ (r & 7);
            const float* src = x + (rowbase + r) * 256 + c * 64 + col16 * 4;
            __builtin_amdgcn_global_load_lds(
                (const __attribute__((address_space(1))) unsigned int*)src,
                (__attribute__((address_space(3))) unsigned int*)
                    (lds + c * 2048 + (w * 8 + h * 4) * 64),
                16, 0, 0);
        }
    }

    f32x4 acc0 = {0.f, 0.f, 0.f, 0.f};
    f32x4 acc1 = {0.f, 0.f, 0.f, 0.f};

    // ---- compute chunk c after counted wait (never drain until the last)
#define CHUNK(C, NWAIT)                                                      \
    {                                                                        \
        asm volatile("s_waitcnt vmcnt(" #NWAIT ")" ::: "memory");            \
        __builtin_amdgcn_s_barrier();                                        \
        __builtin_amdgcn_sched_barrier(0);                                   \
        const float* cb = lds + (C) * 2048;                                  \
        _Pragma("unroll")                                                    \
        for (int ks2 = 0; ks2 < 2; ++ks2) {                                  \
            const int b16 = ks2 * 8 + lq * 2;                                \
            {                                                                \
                const int r = l16;                                           \
                const float* lp = cb + r * 64;                               \
                f32x4 a0 = *(const f32x4*)(lp + (((b16)     ^ (r & 7)) * 4));\
                f32x4 a1 = *(const f32x4*)(lp + (((b16 | 1) ^ (r & 7)) * 4));\
                acc0 = __builtin_amdgcn_mfma_f32_16x16x32_bf16(              \
                    cvt8(a0, a1), wf[(C) * 2 + ks2], acc0, 0, 0, 0);         \
            }                                                                \
            {                                                                \
                const int r = 16 + l16;                                      \
                const float* lp = cb + r * 64;                               \
                f32x4 a0 = *(const f32x4*)(lp + (((b16)     ^ (r & 7)) * 4));\
                f32x4 a1 = *(const f32x4*)(lp + (((b16 | 1) ^ (r & 7)) * 4));\
                acc1 = __builtin_amdgcn_mfma_f32_16x16x32_bf16(              \
                    cvt8(a0, a1), wf[(C) * 2 + ks2], acc1, 0, 0, 0);         \
            }                                                                \
        }                                                                    \
    }

    CHUNK(0, 6)
    CHUNK(1, 4)
    CHUNK(2, 2)
    CHUNK(3, 0)
#undef CHUNK

    // ---- epilogue: C(m,n): n = lane&15, m = (lane>>4)*4 + j; store bf16
    const int col = w * 16 + l16;
    {
        const long r0 = rowbase + lq * 4;
        #pragma unroll
        for (int j = 0; j < 4; ++j)
            y[(r0 + j) * 64 + col] = (__bf16)acc0[j];
    }
    {
        const long r0 = rowbase + 16 + lq * 4;
        #pragma unroll
        for (int j = 0; j < 4; ++j)
            y[(r0 + j) * 64 + col] = (__bf16)acc1[j];
    }
}

// Fused GEMM: blocks [0,4096) L0, [4096,5120) L1, [5120,5376) L2 (32-row tiles)
__global__ __launch_bounds__(256) void gemm_fused(
    const float* __restrict__ x0, const float* __restrict__ x1,
    const float* __restrict__ x2,
    const float* __restrict__ W0, const float* __restrict__ W1,
    const float* __restrict__ W2,
    __bf16* __restrict__ y0, __bf16* __restrict__ y1, __bf16* __restrict__ y2)
{
    __shared__ float lds[4 * 32 * 64];     // 32 KB
    const int b = blockIdx.x;
    if (b < 4096)       gemm_body(b,        lds, x0, W0, y0);
    else if (b < 5120)  gemm_body(b - 4096, lds, x1, W1, y1);
    else                gemm_body(b - 5120, lds, x2, W2, y2);
}

// ------------------------------------------------------------------
// Projection body: per group g, neighbors nh[g][0..7]:
//   logw[p][j] = -(dlat^2+dlon_w^2)/(2 sigma^2) + kappa*(cos(dlon_w)-1)
//   w = softmax_j(logw);  out[n=g*GS+p][d] = sum_j w[p][j]*y[nh[g][j]][d]
// y is bf16 now (half the gather bytes).
// ------------------------------------------------------------------
template<int GS, int CG, int ROUNDS>
__device__ __forceinline__ void proj_body(
    int bid, float (*wlds)[128],
    const __bf16* __restrict__ y,      // [B*N][64] bf16
    const float* __restrict__ coords,  // [2][N]
    const int*   __restrict__ nh,      // [N][8]
    const float* __restrict__ oc,      // [2][B][N0]
    const float* __restrict__ sig_p,
    const float* __restrict__ kap_p,
    float* __restrict__ out,           // [B][N0][64]
    int N, int N0)
{
    constexpr int B = 2;
    static_assert(CG * GS == ROUNDS * 8, "slot layout");

    const int wslot = threadIdx.x >> 6;
    const int lane  = threadIdx.x & 63;
    const int wave  = (bid << 2) + wslot;
    const int gpb   = N / CG;
    const int b     = wave / gpb;
    const int g0    = (wave - b * gpb) * CG;

    const float sigma  = *sig_p;
    const float kappa  = *kap_p;
    const float inv2s2 = 1.0f / (2.0f * sigma * sigma);

    const int j  = lane & 7;
    const int pp = lane >> 3;

    #pragma unroll
    for (int r = 0; r < ROUNDS; ++r) {
        const int pidx = r * 8 + pp;
        const int q = pidx / GS;
        const int p = pidx - q * GS;
        const int g = g0 + q;
        const int idx = nh[g * 8 + j];
        const float clon = coords[idx];
        const float clat = coords[N + idx];
        const int n = g * GS + p;
        const float olon = oc[(long)b * N0 + n];
        const float olat = oc[(long)(B + b) * N0 + n];

        float dlon = olon - clon;
        float t = (dlon + PI_F) * INV_TWO_PI_F;   // floor-mod wrap to [-pi, pi)
        t -= floorf(t);
        dlon = t * TWO_PI_F - PI_F;
        const float dlat = olat - clat;

        float logw = -(dlat * dlat + dlon * dlon) * inv2s2
                   + kappa * (cosf(dlon) - 1.0f);

        float m = logw;
        m = fmaxf(m, __shfl_xor(m, 1));
        m = fmaxf(m, __shfl_xor(m, 2));
        m = fmaxf(m, __shfl_xor(m, 4));
        float e = expf(logw - m);
        float s = e;
        s += __shfl_xor(s, 1);
        s += __shfl_xor(s, 2);
        s += __shfl_xor(s, 4);
        wlds[wslot][r * 64 + lane] = e / s;
    }

    __syncthreads();

    const int d = lane;
    const __bf16* yb = y + (long)b * N * 64 + d;
    #pragma unroll
    for (int pidx = 0; pidx < CG * GS; ++pidx) {
        const int q = pidx / GS;
        const int p = pidx - q * GS;
        const int g = g0 + q;
        const int* nhg = nh + g * 8;
        const float* wrow = &wlds[wslot][(pidx >> 3) * 64 + (pidx & 7) * 8];
        float a = 0.0f;
        #pragma unroll
        for (int jj = 0; jj < 8; ++jj)
            a = fmaf(wrow[jj], (float)yb[(long)nhg[jj] * 64], a);
        const int n = g * GS + p;
        out[((long)b * N0 + n) * 64 + d] = a;
    }
}

// Fused projection: blocks [0,4096) L0, [4096,8192) L1, [8192,10240) L2.
__global__ __launch_bounds__(256) void proj_fused(
    const __bf16* __restrict__ y0, const __bf16* __restrict__ y1,
    const __bf16* __restrict__ y2,
    const float* __restrict__ c0, const float* __restrict__ c1,
    const float* __restrict__ c2,
    const int* __restrict__ nh0, const int* __restrict__ nh1,
    const int* __restrict__ nh2,
    const float* __restrict__ oc,
    const float* __restrict__ sig0, const float* __restrict__ sig1,
    const float* __restrict__ sig2,
    const float* __restrict__ kap0, const float* __restrict__ kap1,
    const float* __restrict__ kap2,
    float* __restrict__ out)
{
    __shared__ float wlds[4][128];
    const size_t SLICE = (size_t)2 * 65536 * 64;
    const int b = blockIdx.x;
    if (b < 4096)
        proj_body<1, 8, 1>(b, wlds, y0, c0, nh0, oc, sig0, kap0,
                           out, 65536, 65536);
    else if (b < 8192)
        proj_body<4, 2, 1>(b - 4096, wlds, y1, c1, nh1, oc, sig1, kap1,
                           out + SLICE, 16384, 65536);
    else
        proj_body<16, 1, 2>(b - 8192, wlds, y2, c2, nh2, oc, sig2, kap2,
                            out + 2 * SLICE, 4096, 65536);
}

// ------------------------------------------------------------------
extern "C" void kernel_launch(void* const* d_in, const int* in_sizes, int n_in,
                              void* d_out, int out_size, void* d_ws, size_t ws_size,
                              hipStream_t stream)
{
    const float* x0   = (const float*)d_in[0];
    const float* x1   = (const float*)d_in[1];
    const float* x2   = (const float*)d_in[2];
    const float* W0   = (const float*)d_in[3];
    const float* W1   = (const float*)d_in[4];
    const float* W2   = (const float*)d_in[5];
    const float* sig0 = (const float*)d_in[6];
    const float* sig1 = (const float*)d_in[7];
    const float* sig2 = (const float*)d_in[8];
    const float* kap0 = (const float*)d_in[9];
    const float* kap1 = (const float*)d_in[10];
    const float* kap2 = (const float*)d_in[11];
    const float* c0   = (const float*)d_in[12];
    const float* c1   = (const float*)d_in[13];
    const float* c2   = (const float*)d_in[14];
    const int*   nh0  = (const int*)d_in[15];
    const int*   nh1  = (const int*)d_in[16];
    const int*   nh2  = (const int*)d_in[17];
    const float* oc   = (const float*)d_in[18];

    float* out = (float*)d_out;
    // y staging (bf16) in d_ws: 16.8 + 4.2 + 1.05 MB
    __bf16* y0 = (__bf16*)d_ws;
    __bf16* y1 = y0 + (size_t)2 * 65536 * 64;
    __bf16* y2 = y1 + (size_t)2 * 16384 * 64;

    gemm_fused<<<5376, 256, 0, stream>>>(x0, x1, x2, W0, W1, W2, y0, y1, y2);
    proj_fused<<<10240, 256, 0, stream>>>(y0, y1, y2, c0, c1, c2,
                                          nh0, nh1, nh2, oc,
                                          sig0, sig1, sig2,
                                          kap0, kap1, kap2, out);
}

// Round 9
// 96.181 us; speedup vs baseline: 4.8292x; 1.1691x over previous
//
#include <hip/hip_runtime.h>
#include <math.h>

#define PI_F        3.14159265358979323846f
#define TWO_PI_F    6.2831853071795864769f
#define INV_TWO_PI_F 0.15915494309189533577f

typedef __attribute__((ext_vector_type(8))) short  bf16x8;
typedef __attribute__((ext_vector_type(8))) __bf16 bf16v8;
typedef __attribute__((ext_vector_type(4))) float  f32x4;

__device__ __forceinline__ bf16x8 cvt8(f32x4 a, f32x4 b) {
    bf16v8 v;
    v[0] = (__bf16)a.x; v[1] = (__bf16)a.y; v[2] = (__bf16)a.z; v[3] = (__bf16)a.w;
    v[4] = (__bf16)b.x; v[5] = (__bf16)b.y; v[6] = (__bf16)b.z; v[7] = (__bf16)b.w;
    return __builtin_bit_cast(bf16x8, v);
}

// ------------------------------------------------------------------
// W prep: convert W (f32 [64][256], torch layout) into bf16 MFMA
// B-fragment layout: wfb[level][(w*8+ks)*64 + lane] = 8 bf16 such that
// gemm wave w, lane l, k-slice ks reads W[w*16+(l&15)][ks*32+(l>>4)*8 ..+8].
// 8 blocks x 256 thr per level; each thread emits one 16B fragment.
// ------------------------------------------------------------------
__global__ __launch_bounds__(256) void wprep(
    const float* __restrict__ W0, const float* __restrict__ W1,
    const float* __restrict__ W2, __bf16* __restrict__ wfb)
{
    const int level = blockIdx.x >> 3;
    const int rem   = ((blockIdx.x & 7) << 8) | threadIdx.x;   // 0..2047
    const float* W  = level == 0 ? W0 : (level == 1 ? W1 : W2);
    const int l  = rem & 63;
    const int ks = (rem >> 6) & 7;
    const int w  = rem >> 9;
    const int col = w * 16 + (l & 15);
    const int k0  = ks * 32 + (l >> 4) * 8;
    const float* wp = W + col * 256 + k0;
    bf16x8 f = cvt8(*(const f32x4*)wp, *(const f32x4*)(wp + 4));
    *(bf16x8*)(wfb + (size_t)level * 16384 + (size_t)rem * 8) = f;
}

// ------------------------------------------------------------------
// bf16-MFMA GEMM, counted-vmcnt streaming: y = x (.) W^T, K=256, Do=64,
// y stored bf16. 256 thr = 4 waves; wave w owns cols [w*16,w*16+16),
// 32 tile rows (2 m-tiles). W-frags: 8 contiguous dwordx4/wave from the
// prepped fragment array (issued FIRST -> oldest in vmcnt order).
// x tile staged as 4 chunks of K=64 (chunk-major LDS [4][32][64] f32)
// via global_load_lds; chunk-c wait = s_waitcnt vmcnt((3-c)*2), so later
// chunks' DMAs never drain. Source-side 16B-chunk XOR swizzle
// (col16 ^= r&7) keeps ds_read conflicts ~2-way (free).
// MFMA 16x16x32: A(m,k): lane=(k>>3)*16+m, slots k&7.
//                B(k,n): lane=(k>>3)*16+n.
//                C(m,n): n=lane&15, m=(lane>>4)*4+reg.
// ------------------------------------------------------------------
__device__ __forceinline__ void gemm_body(
    int bid, float* lds,               // [4][32][64] f32, chunk-major
    const float* __restrict__ x, const __bf16* __restrict__ wfb,
    __bf16* __restrict__ y)
{
    const int tid  = threadIdx.x;
    const int lane = tid & 63;
    const int w    = tid >> 6;
    const int l16  = lane & 15;
    const int lq   = lane >> 4;
    const long rowbase = (long)bid * 32;

    // ---- W fragments: 8 contiguous 16B loads (oldest VMEM ops)
    bf16x8 wf[8];
    {
        const __bf16* wb = wfb + (size_t)w * 4096 + (size_t)lane * 8;
        #pragma unroll
        for (int ks = 0; ks < 8; ++ks)
            wf[ks] = *(const bf16x8*)(wb + ks * 512);
    }
    __builtin_amdgcn_sched_barrier(0);   // pin: wf loads issue before DMAs

    // ---- stage x: 8 DMA issues, chunk-major. Issue (c,h):
    // rows r = w*8+h*4 + (lane>>4), source 16B-chunk = (lane&15)^(r&7).
    #pragma unroll
    for (int c = 0; c < 4; ++c) {
        #pragma unroll
        for (int h = 0; h < 2; ++h) {
            const int r = w * 8 + h * 4 + (lane >> 4);
            const int col16 = (lane & 15) ^ (r & 7);
            const float* src = x + (rowbase + r) * 256 + c * 64 + col16 * 4;
            __builtin_amdgcn_global_load_lds(
                (const __attribute__((address_space(1))) unsigned int*)src,
                (__attribute__((address_space(3))) unsigned int*)
                    (lds + c * 2048 + (w * 8 + h * 4) * 64),
                16, 0, 0);
        }
    }
    __builtin_amdgcn_sched_barrier(0);   // pin: all DMAs issued here

    f32x4 acc0 = {0.f, 0.f, 0.f, 0.f};
    f32x4 acc1 = {0.f, 0.f, 0.f, 0.f};

    // ---- compute chunk c after counted wait (only the last drains)
#define CHUNK(C, NWAIT)                                                      \
    {                                                                        \
        asm volatile("s_waitcnt vmcnt(" #NWAIT ")" ::: "memory");            \
        __builtin_amdgcn_s_barrier();                                        \
        __builtin_amdgcn_sched_barrier(0);                                   \
        const float* cb = lds + (C) * 2048;                                  \
        _Pragma("unroll")                                                    \
        for (int ks2 = 0; ks2 < 2; ++ks2) {                                  \
            const int b16 = ks2 * 8 + lq * 2;                                \
            {                                                                \
                const int r = l16;                                           \
                const float* lp = cb + r * 64;                               \
                f32x4 a0 = *(const f32x4*)(lp + (((b16)     ^ (r & 7)) * 4));\
                f32x4 a1 = *(const f32x4*)(lp + (((b16 | 1) ^ (r & 7)) * 4));\
                acc0 = __builtin_amdgcn_mfma_f32_16x16x32_bf16(              \
                    cvt8(a0, a1), wf[(C) * 2 + ks2], acc0, 0, 0, 0);         \
            }                                                                \
            {                                                                \
                const int r = 16 + l16;                                      \
                const float* lp = cb + r * 64;                               \
                f32x4 a0 = *(const f32x4*)(lp + (((b16)     ^ (r & 7)) * 4));\
                f32x4 a1 = *(const f32x4*)(lp + (((b16 | 1) ^ (r & 7)) * 4));\
                acc1 = __builtin_amdgcn_mfma_f32_16x16x32_bf16(              \
                    cvt8(a0, a1), wf[(C) * 2 + ks2], acc1, 0, 0, 0);         \
            }                                                                \
        }                                                                    \
    }

    CHUNK(0, 6)
    CHUNK(1, 4)
    CHUNK(2, 2)
    CHUNK(3, 0)
#undef CHUNK

    // ---- epilogue: C(m,n): n = lane&15, m = (lane>>4)*4 + j; store bf16
    const int col = w * 16 + l16;
    {
        const long r0 = rowbase + lq * 4;
        #pragma unroll
        for (int j = 0; j < 4; ++j)
            y[(r0 + j) * 64 + col] = (__bf16)acc0[j];
    }
    {
        const long r0 = rowbase + 16 + lq * 4;
        #pragma unroll
        for (int j = 0; j < 4; ++j)
            y[(r0 + j) * 64 + col] = (__bf16)acc1[j];
    }
}

// Fused GEMM: blocks [0,4096) L0, [4096,5120) L1, [5120,5376) L2 (32-row tiles)
__global__ __launch_bounds__(256) void gemm_fused(
    const float* __restrict__ x0, const float* __restrict__ x1,
    const float* __restrict__ x2,
    const __bf16* __restrict__ wfb,
    __bf16* __restrict__ y0, __bf16* __restrict__ y1, __bf16* __restrict__ y2)
{
    __shared__ float lds[4 * 32 * 64];     // 32 KB
    const int b = blockIdx.x;
    if (b < 4096)       gemm_body(b,        lds, x0, wfb,         y0);
    else if (b < 5120)  gemm_body(b - 4096, lds, x1, wfb + 16384, y1);
    else                gemm_body(b - 5120, lds, x2, wfb + 32768, y2);
}

// ------------------------------------------------------------------
// Projection body: per group g, neighbors nh[g][0..7]:
//   logw[p][j] = -(dlat^2+dlon_w^2)/(2 sigma^2) + kappa*(cos(dlon_w)-1)
//   w = softmax_j(logw);  out[n=g*GS+p][d] = sum_j w[p][j]*y[nh[g][j]][d]
// ------------------------------------------------------------------
template<int GS, int CG, int ROUNDS>
__device__ __forceinline__ void proj_body(
    int bid, float (*wlds)[128],
    const __bf16* __restrict__ y,      // [B*N][64] bf16
    const float* __restrict__ coords,  // [2][N]
    const int*   __restrict__ nh,      // [N][8]
    const float* __restrict__ oc,      // [2][B][N0]
    const float* __restrict__ sig_p,
    const float* __restrict__ kap_p,
    float* __restrict__ out,           // [B][N0][64]
    int N, int N0)
{
    constexpr int B = 2;
    static_assert(CG * GS == ROUNDS * 8, "slot layout");

    const int wslot = threadIdx.x >> 6;
    const int lane  = threadIdx.x & 63;
    const int wave  = (bid << 2) + wslot;
    const int gpb   = N / CG;
    const int b     = wave / gpb;
    const int g0    = (wave - b * gpb) * CG;

    const float sigma  = *sig_p;
    const float kappa  = *kap_p;
    const float inv2s2 = 1.0f / (2.0f * sigma * sigma);

    const int j  = lane & 7;
    const int pp = lane >> 3;

    #pragma unroll
    for (int r = 0; r < ROUNDS; ++r) {
        const int pidx = r * 8 + pp;
        const int q = pidx / GS;
        const int p = pidx - q * GS;
        const int g = g0 + q;
        const int idx = nh[g * 8 + j];
        const float clon = coords[idx];
        const float clat = coords[N + idx];
        const int n = g * GS + p;
        const float olon = oc[(long)b * N0 + n];
        const float olat = oc[(long)(B + b) * N0 + n];

        float dlon = olon - clon;
        float t = (dlon + PI_F) * INV_TWO_PI_F;   // floor-mod wrap to [-pi, pi)
        t -= floorf(t);
        dlon = t * TWO_PI_F - PI_F;
        const float dlat = olat - clat;

        float logw = -(dlat * dlat + dlon * dlon) * inv2s2
                   + kappa * (cosf(dlon) - 1.0f);

        float m = logw;
        m = fmaxf(m, __shfl_xor(m, 1));
        m = fmaxf(m, __shfl_xor(m, 2));
        m = fmaxf(m, __shfl_xor(m, 4));
        float e = expf(logw - m);
        float s = e;
        s += __shfl_xor(s, 1);
        s += __shfl_xor(s, 2);
        s += __shfl_xor(s, 4);
        wlds[wslot][r * 64 + lane] = e / s;
    }

    __syncthreads();

    const int d = lane;
    const __bf16* yb = y + (long)b * N * 64 + d;
    #pragma unroll
    for (int pidx = 0; pidx < CG * GS; ++pidx) {
        const int q = pidx / GS;
        const int p = pidx - q * GS;
        const int g = g0 + q;
        const int* nhg = nh + g * 8;
        const float* wrow = &wlds[wslot][(pidx >> 3) * 64 + (pidx & 7) * 8];
        float a = 0.0f;
        #pragma unroll
        for (int jj = 0; jj < 8; ++jj)
            a = fmaf(wrow[jj], (float)yb[(long)nhg[jj] * 64], a);
        const int n = g * GS + p;
        out[((long)b * N0 + n) * 64 + d] = a;
    }
}

// Fused projection: blocks [0,4096) L0, [4096,8192) L1, [8192,10240) L2.
__global__ __launch_bounds__(256) void proj_fused(
    const __bf16* __restrict__ y0, const __bf16* __restrict__ y1,
    const __bf16* __restrict__ y2,
    const float* __restrict__ c0, const float* __restrict__ c1,
    const float* __restrict__ c2,
    const int* __restrict__ nh0, const int* __restrict__ nh1,
    const int* __restrict__ nh2,
    const float* __restrict__ oc,
    const float* __restrict__ sig0, const float* __restrict__ sig1,
    const float* __restrict__ sig2,
    const float* __restrict__ kap0, const float* __restrict__ kap1,
    const float* __restrict__ kap2,
    float* __restrict__ out)
{
    __shared__ float wlds[4][128];
    const size_t SLICE = (size_t)2 * 65536 * 64;
    const int b = blockIdx.x;
    if (b < 4096)
        proj_body<1, 8, 1>(b, wlds, y0, c0, nh0, oc, sig0, kap0,
                           out, 65536, 65536);
    else if (b < 8192)
        proj_body<4, 2, 1>(b - 4096, wlds, y1, c1, nh1, oc, sig1, kap1,
                           out + SLICE, 16384, 65536);
    else
        proj_body<16, 1, 2>(b - 8192, wlds, y2, c2, nh2, oc, sig2, kap2,
                            out + 2 * SLICE, 4096, 65536);
}

// ------------------------------------------------------------------
extern "C" void kernel_launch(void* const* d_in, const int* in_sizes, int n_in,
                              void* d_out, int out_size, void* d_ws, size_t ws_size,
                              hipStream_t stream)
{
    const float* x0   = (const float*)d_in[0];
    const float* x1   = (const float*)d_in[1];
    const float* x2   = (const float*)d_in[2];
    const float* W0   = (const float*)d_in[3];
    const float* W1   = (const float*)d_in[4];
    const float* W2   = (const float*)d_in[5];
    const float* sig0 = (const float*)d_in[6];
    const float* sig1 = (const float*)d_in[7];
    const float* sig2 = (const float*)d_in[8];
    const float* kap0 = (const float*)d_in[9];
    const float* kap1 = (const float*)d_in[10];
    const float* kap2 = (const float*)d_in[11];
    const float* c0   = (const float*)d_in[12];
    const float* c1   = (const float*)d_in[13];
    const float* c2   = (const float*)d_in[14];
    const int*   nh0  = (const int*)d_in[15];
    const int*   nh1  = (const int*)d_in[16];
    const int*   nh2  = (const int*)d_in[17];
    const float* oc   = (const float*)d_in[18];

    float* out = (float*)d_out;
    // d_ws layout (bf16 elements): wfb[3*16384] | y0 | y1 | y2
    __bf16* wfb = (__bf16*)d_ws;
    __bf16* y0  = wfb + 3 * 16384;
    __bf16* y1  = y0 + (size_t)2 * 65536 * 64;
    __bf16* y2  = y1 + (size_t)2 * 16384 * 64;

    wprep<<<24, 256, 0, stream>>>(W0, W1, W2, wfb);
    gemm_fused<<<5376, 256, 0, stream>>>(x0, x1, x2, wfb, y0, y1, y2);
    proj_fused<<<10240, 256, 0, stream>>>(y0, y1, y2, c0, c1, c2,
                                          nh0, nh1, nh2, oc,
                                          sig0, sig1, sig2,
                                          kap0, kap1, kap2, out);
}